// Round 1
// baseline (8411.507 us; speedup 1.0000x reference)
//
#include <hip/hip_runtime.h>

#define H 256
#define NNODE 50000   // both N_PEP and N_PROT

// ---------------------------------------------------------------------------
// GEMM: C[M,N] = A[M,K] @ W[N,K]^T (+ bias[N]) (+= existing C) (relu)
// 64x64 tile, BK=16, 256 threads, 4x4 micro-tile per thread.
// LDS stored transposed [k][row] with stride 68 (16B-aligned, conflict-light).
// ---------------------------------------------------------------------------
template<bool ACCUM, bool RELU>
__global__ __launch_bounds__(256) void gemm_nt(
    const float* __restrict__ A, const float* __restrict__ W,
    const float* __restrict__ bias, float* __restrict__ C,
    int M, int N, int K)
{
    constexpr int LS = 68; // floats; 68*4=272 bytes, multiple of 16
    __shared__ __align__(16) float As[16 * LS];
    __shared__ __align__(16) float Bs[16 * LS];

    const int tid = threadIdx.x;
    const int tx = tid & 15;   // col group (cols n0 + tx*4 .. +3)
    const int ty = tid >> 4;   // row group (rows m0 + ty*4 .. +3)
    const int m0 = blockIdx.x * 64;
    const int n0 = blockIdx.y * 64;
    const int lr = tid >> 2;        // 0..63  tile row for staging
    const int lk = (tid & 3) * 4;   // 0,4,8,12 k offset for staging

    float acc[4][4] = {};

    const bool arow_ok = (m0 + lr) < M;
    const float* Aptr = A + (size_t)(m0 + lr) * K + lk;
    const float* Wptr = W + (size_t)(n0 + lr) * K + lk;

    for (int k0 = 0; k0 < K; k0 += 16) {
        float4 av = make_float4(0.f, 0.f, 0.f, 0.f);
        if (arow_ok) av = *(const float4*)(Aptr + k0);
        float4 bv = *(const float4*)(Wptr + k0);
        As[(lk + 0) * LS + lr] = av.x;
        As[(lk + 1) * LS + lr] = av.y;
        As[(lk + 2) * LS + lr] = av.z;
        As[(lk + 3) * LS + lr] = av.w;
        Bs[(lk + 0) * LS + lr] = bv.x;
        Bs[(lk + 1) * LS + lr] = bv.y;
        Bs[(lk + 2) * LS + lr] = bv.z;
        Bs[(lk + 3) * LS + lr] = bv.w;
        __syncthreads();
#pragma unroll
        for (int k = 0; k < 16; ++k) {
            float4 a4 = *(const float4*)&As[k * LS + ty * 4];
            float4 b4 = *(const float4*)&Bs[k * LS + tx * 4];
            float a[4] = {a4.x, a4.y, a4.z, a4.w};
            float b[4] = {b4.x, b4.y, b4.z, b4.w};
#pragma unroll
            for (int i = 0; i < 4; ++i)
#pragma unroll
                for (int j = 0; j < 4; ++j)
                    acc[i][j] = fmaf(a[i], b[j], acc[i][j]);
        }
        __syncthreads();
    }

    float bvals[4] = {0.f, 0.f, 0.f, 0.f};
    if (bias) {
        float4 t = *(const float4*)(bias + n0 + tx * 4);
        bvals[0] = t.x; bvals[1] = t.y; bvals[2] = t.z; bvals[3] = t.w;
    }
#pragma unroll
    for (int i = 0; i < 4; ++i) {
        int row = m0 + ty * 4 + i;
        if (row >= M) continue;
        float* crow = C + (size_t)row * N + n0 + tx * 4;
        float4 v;
        v.x = acc[i][0] + bvals[0];
        v.y = acc[i][1] + bvals[1];
        v.z = acc[i][2] + bvals[2];
        v.w = acc[i][3] + bvals[3];
        if (ACCUM) {
            float4 o = *(const float4*)crow;
            v.x += o.x; v.y += o.y; v.z += o.z; v.w += o.w;
        }
        if (RELU) {
            v.x = fmaxf(v.x, 0.f); v.y = fmaxf(v.y, 0.f);
            v.z = fmaxf(v.z, 0.f); v.w = fmaxf(v.w, 0.f);
        }
        *(float4*)crow = v;
    }
}

// ---------------------------------------------------------------------------
// zero fill
// ---------------------------------------------------------------------------
__global__ __launch_bounds__(256) void fill_zero(float4* __restrict__ p, size_t n4)
{
    size_t i = (size_t)blockIdx.x * blockDim.x + threadIdx.x;
    size_t stride = (size_t)gridDim.x * blockDim.x;
    for (; i < n4; i += stride) p[i] = make_float4(0.f, 0.f, 0.f, 0.f);
}

// ---------------------------------------------------------------------------
// scatter-add: one wave (64 lanes) per edge; row of 256 floats as float4/lane
// ---------------------------------------------------------------------------
__global__ __launch_bounds__(256) void scatter_add(
    const float* __restrict__ feat, const int* __restrict__ src_idx,
    const int* __restrict__ dst_idx, int nE,
    float* __restrict__ agg, float* __restrict__ cnt)
{
    int e = (int)(((size_t)blockIdx.x * blockDim.x + threadIdx.x) >> 6);
    int lane = threadIdx.x & 63;
    if (e >= nE) return;
    int s = src_idx[e];
    int d = dst_idx[e];
    float4 v = ((const float4*)(feat + (size_t)s * H))[lane];
    float* drow = agg + (size_t)d * H + lane * 4;
    atomicAdd(drow + 0, v.x);
    atomicAdd(drow + 1, v.y);
    atomicAdd(drow + 2, v.z);
    atomicAdd(drow + 3, v.w);
    if (lane == 0) atomicAdd(cnt + d, 1.0f);
}

// ---------------------------------------------------------------------------
// divide rows by max(cnt,1):  agg[r,:] /= max(cnt[r],1)
// ---------------------------------------------------------------------------
__global__ __launch_bounds__(256) void divide_cnt(
    float4* __restrict__ agg, const float* __restrict__ cnt, int n_rows)
{
    size_t total = (size_t)n_rows * (H / 4);
    size_t i = (size_t)blockIdx.x * blockDim.x + threadIdx.x;
    if (i >= total) return;
    int row = (int)(i >> 6);  // H/4 = 64 float4 per row
    float inv = 1.0f / fmaxf(cnt[row], 1.0f);
    float4 v = agg[i];
    v.x *= inv; v.y *= inv; v.z *= inv; v.w *= inv;
    agg[i] = v;
}

// ---------------------------------------------------------------------------
// edge dot: out[e] = dot(P[ia[e]], Q[ib[e]]), one wave per edge
// ---------------------------------------------------------------------------
__global__ __launch_bounds__(256) void edge_dot(
    const float* __restrict__ P, const float* __restrict__ Q,
    const int* __restrict__ ia, const int* __restrict__ ib,
    int nE, float* __restrict__ out)
{
    int e = (int)(((size_t)blockIdx.x * blockDim.x + threadIdx.x) >> 6);
    int lane = threadIdx.x & 63;
    if (e >= nE) return;
    float4 a = ((const float4*)(P + (size_t)ia[e] * H))[lane];
    float4 b = ((const float4*)(Q + (size_t)ib[e] * H))[lane];
    float v = a.x * b.x + a.y * b.y + a.z * b.z + a.w * b.w;
#pragma unroll
    for (int off = 32; off; off >>= 1) v += __shfl_down(v, off);
    if (lane == 0) out[e] = v;
}

// ---------------------------------------------------------------------------
// host-side helpers
// ---------------------------------------------------------------------------
static inline void launch_gemm(const float* A, const float* W, const float* bias,
                               float* C, int M, int N, int K,
                               bool accum, bool relu, hipStream_t s)
{
    dim3 grid((M + 63) / 64, N / 64);
    dim3 block(256);
    if (accum) {
        if (relu) gemm_nt<true, true><<<grid, block, 0, s>>>(A, W, bias, C, M, N, K);
        else      gemm_nt<true, false><<<grid, block, 0, s>>>(A, W, bias, C, M, N, K);
    } else {
        if (relu) gemm_nt<false, true><<<grid, block, 0, s>>>(A, W, bias, C, M, N, K);
        else      gemm_nt<false, false><<<grid, block, 0, s>>>(A, W, bias, C, M, N, K);
    }
}

static inline void launch_seg_mean(const float* feat, const int* ei, int E,
                                   int n_dst, float* agg, float* cnt, hipStream_t s)
{
    size_t n4 = (size_t)n_dst * H / 4;
    fill_zero<<<2048, 256, 0, s>>>((float4*)agg, n4);
    fill_zero<<<64, 256, 0, s>>>((float4*)cnt, (size_t)n_dst / 4);
    scatter_add<<<(E + 3) / 4, 256, 0, s>>>(feat, ei, ei + E, E, agg, cnt);
    divide_cnt<<<(int)((n4 + 255) / 256), 256, 0, s>>>((float4*)agg, cnt, n_dst);
}

extern "C" void kernel_launch(void* const* d_in, const int* in_sizes, int n_in,
                              void* d_out, int out_size, void* d_ws, size_t ws_size,
                              hipStream_t stream)
{
    const float* x_pep  = (const float*)d_in[0];
    const float* x_prot = (const float*)d_in[1];
    const float* Wpep   = (const float*)d_in[2];
    const float* bpep   = (const float*)d_in[3];
    const float* Wprot  = (const float*)d_in[4];
    const float* bprot  = (const float*)d_in[5];
    const float* Wl1    = (const float*)d_in[6];
    const float* bl1    = (const float*)d_in[7];
    const float* Wr1    = (const float*)d_in[8];
    const float* Wl2    = (const float*)d_in[9];
    const float* bl2    = (const float*)d_in[10];
    const float* Wr2    = (const float*)d_in[11];
    const int* ei_pp    = (const int*)d_in[12];
    const int* ei_rp    = (const int*)d_in[13];
    const int* ei_prot  = (const int*)d_in[14];
    const int* eli_het  = (const int*)d_in[15];
    const int* eli_homo = (const int*)d_in[16];

    const int E   = in_sizes[12] / 2;   // 300000
    const int EL  = in_sizes[15] / 2;   // 200000
    const int FIN = in_sizes[2] / H;    // 1280

    float* out = (float*)d_out;

    // workspace: 5 node buffers (50000x256 f32) + cnt (50000 f32) = 244.4 MiB
    const size_t nodeElems = (size_t)NNODE * H;
    float* bufA = (float*)d_ws;          // h_pep   -> p2
    float* bufB = bufA + nodeElems;      // h_prot  -> q2
    float* bufC = bufB + nodeElems;      // p1
    float* bufD = bufC + nodeElems;      // q1
    float* bufE = bufD + nodeElems;      // seg-mean scratch
    float* cnt  = bufE + nodeElems;      // 50000 floats

    const size_t HH = (size_t)H * H;

    // --- input projections -------------------------------------------------
    launch_gemm(x_pep,  Wpep,  bpep,  bufA, NNODE, H, FIN, false, false, stream); // h_pep
    launch_gemm(x_prot, Wprot, bprot, bufB, NNODE, H, FIN, false, false, stream); // h_prot

    // --- layer 1: p1 = relu(sage(h_prot -> pep via ei_rp)) ------------------
    launch_seg_mean(bufB, ei_rp, E, NNODE, bufE, cnt, stream);
    launch_gemm(bufE, Wl1 + 1 * HH, bl1 + 1 * H, bufC, NNODE, H, H, false, false, stream);
    launch_gemm(bufA, Wr1 + 1 * HH, nullptr,     bufC, NNODE, H, H, true,  true,  stream); // relu

    // --- layer 1: q1 = relu(sage(pep->prot, ei_pp) + sage(prot->prot, ei_prot))
    launch_seg_mean(bufA, ei_pp, E, NNODE, bufE, cnt, stream);
    launch_gemm(bufE, Wl1 + 0 * HH, bl1 + 0 * H, bufD, NNODE, H, H, false, false, stream);
    launch_gemm(bufB, Wr1 + 0 * HH, nullptr,     bufD, NNODE, H, H, true,  false, stream);
    launch_seg_mean(bufB, ei_prot, E, NNODE, bufE, cnt, stream);
    launch_gemm(bufE, Wl1 + 2 * HH, bl1 + 2 * H, bufD, NNODE, H, H, true,  false, stream);
    launch_gemm(bufB, Wr1 + 2 * HH, nullptr,     bufD, NNODE, H, H, true,  true,  stream); // relu

    // --- layer 2: p2 = sage(q1 -> pep via ei_rp) + p1 @ Wr2[1]^T  (into bufA)
    launch_seg_mean(bufD, ei_rp, E, NNODE, bufE, cnt, stream);
    launch_gemm(bufE, Wl2 + 1 * HH, bl2 + 1 * H, bufA, NNODE, H, H, false, false, stream);
    launch_gemm(bufC, Wr2 + 1 * HH, nullptr,     bufA, NNODE, H, H, true,  false, stream);

    // --- layer 2: q2 = sage(p1->prot, ei_pp) + sage(q1->prot, ei_prot) (into bufB)
    launch_seg_mean(bufC, ei_pp, E, NNODE, bufE, cnt, stream);
    launch_gemm(bufE, Wl2 + 0 * HH, bl2 + 0 * H, bufB, NNODE, H, H, false, false, stream);
    launch_gemm(bufD, Wr2 + 0 * HH, nullptr,     bufB, NNODE, H, H, true,  false, stream);
    launch_seg_mean(bufD, ei_prot, E, NNODE, bufE, cnt, stream);
    launch_gemm(bufE, Wl2 + 2 * HH, bl2 + 2 * H, bufB, NNODE, H, H, true,  false, stream);
    launch_gemm(bufD, Wr2 + 2 * HH, nullptr,     bufB, NNODE, H, H, true,  false, stream);

    // --- edge classifiers ----------------------------------------------------
    edge_dot<<<(EL + 3) / 4, 256, 0, stream>>>(bufA, bufB, eli_het,  eli_het  + EL, EL, out);
    edge_dot<<<(EL + 3) / 4, 256, 0, stream>>>(bufB, bufB, eli_homo, eli_homo + EL, EL, out + EL);
}

// Round 2
// 2625.930 us; speedup vs baseline: 3.2032x; 3.2032x over previous
//
#include <hip/hip_runtime.h>

#define H 256
#define NNODE 50000   // both N_PEP and N_PROT
#define CAP 64        // max in-degree stored per node (Poisson(6): P(X>=64)~1e-41)

// ---------------------------------------------------------------------------
// GEMM: C[M,N] = A[M,K] @ W[N,K]^T (+ bias[N]) (+= existing C) (relu)
// 64x64 tile, BK=16, 256 threads, 4x4 micro-tile per thread.
// ---------------------------------------------------------------------------
template<bool ACCUM, bool RELU>
__global__ __launch_bounds__(256) void gemm_nt(
    const float* __restrict__ A, const float* __restrict__ W,
    const float* __restrict__ bias, float* __restrict__ C,
    int M, int N, int K)
{
    constexpr int LS = 68; // floats; 68*4=272 bytes, multiple of 16
    __shared__ __align__(16) float As[16 * LS];
    __shared__ __align__(16) float Bs[16 * LS];

    const int tid = threadIdx.x;
    const int tx = tid & 15;   // col group (cols n0 + tx*4 .. +3)
    const int ty = tid >> 4;   // row group (rows m0 + ty*4 .. +3)
    const int m0 = blockIdx.x * 64;
    const int n0 = blockIdx.y * 64;
    const int lr = tid >> 2;        // 0..63  tile row for staging
    const int lk = (tid & 3) * 4;   // 0,4,8,12 k offset for staging

    float acc[4][4] = {};

    const bool arow_ok = (m0 + lr) < M;
    const float* Aptr = A + (size_t)(m0 + lr) * K + lk;
    const float* Wptr = W + (size_t)(n0 + lr) * K + lk;

    for (int k0 = 0; k0 < K; k0 += 16) {
        float4 av = make_float4(0.f, 0.f, 0.f, 0.f);
        if (arow_ok) av = *(const float4*)(Aptr + k0);
        float4 bv = *(const float4*)(Wptr + k0);
        As[(lk + 0) * LS + lr] = av.x;
        As[(lk + 1) * LS + lr] = av.y;
        As[(lk + 2) * LS + lr] = av.z;
        As[(lk + 3) * LS + lr] = av.w;
        Bs[(lk + 0) * LS + lr] = bv.x;
        Bs[(lk + 1) * LS + lr] = bv.y;
        Bs[(lk + 2) * LS + lr] = bv.z;
        Bs[(lk + 3) * LS + lr] = bv.w;
        __syncthreads();
#pragma unroll
        for (int k = 0; k < 16; ++k) {
            float4 a4 = *(const float4*)&As[k * LS + ty * 4];
            float4 b4 = *(const float4*)&Bs[k * LS + tx * 4];
            float a[4] = {a4.x, a4.y, a4.z, a4.w};
            float b[4] = {b4.x, b4.y, b4.z, b4.w};
#pragma unroll
            for (int i = 0; i < 4; ++i)
#pragma unroll
                for (int j = 0; j < 4; ++j)
                    acc[i][j] = fmaf(a[i], b[j], acc[i][j]);
        }
        __syncthreads();
    }

    float bvals[4] = {0.f, 0.f, 0.f, 0.f};
    if (bias) {
        float4 t = *(const float4*)(bias + n0 + tx * 4);
        bvals[0] = t.x; bvals[1] = t.y; bvals[2] = t.z; bvals[3] = t.w;
    }
#pragma unroll
    for (int i = 0; i < 4; ++i) {
        int row = m0 + ty * 4 + i;
        if (row >= M) continue;
        float* crow = C + (size_t)row * N + n0 + tx * 4;
        float4 v;
        v.x = acc[i][0] + bvals[0];
        v.y = acc[i][1] + bvals[1];
        v.z = acc[i][2] + bvals[2];
        v.w = acc[i][3] + bvals[3];
        if (ACCUM) {
            float4 o = *(const float4*)crow;
            v.x += o.x; v.y += o.y; v.z += o.z; v.w += o.w;
        }
        if (RELU) {
            v.x = fmaxf(v.x, 0.f); v.y = fmaxf(v.y, 0.f);
            v.z = fmaxf(v.z, 0.f); v.w = fmaxf(v.w, 0.f);
        }
        *(float4*)crow = v;
    }
}

// ---------------------------------------------------------------------------
// zero fill (works for any 16B-multiple region)
// ---------------------------------------------------------------------------
__global__ __launch_bounds__(256) void fill_zero(float4* __restrict__ p, size_t n4)
{
    size_t i = (size_t)blockIdx.x * blockDim.x + threadIdx.x;
    size_t stride = (size_t)gridDim.x * blockDim.x;
    for (; i < n4; i += stride) p[i] = make_float4(0.f, 0.f, 0.f, 0.f);
}

// ---------------------------------------------------------------------------
// bucket build: for each edge, append src into dst's bucket (int atomics only)
// ---------------------------------------------------------------------------
__global__ __launch_bounds__(256) void build_bucket(
    const int* __restrict__ src, const int* __restrict__ dst, int nE,
    int* __restrict__ cnt, int* __restrict__ bucket)
{
    int i = blockIdx.x * blockDim.x + threadIdx.x;
    if (i >= nE) return;
    int d = dst[i];
    int pos = atomicAdd(&cnt[d], 1);
    if (pos < CAP) bucket[(size_t)d * CAP + pos] = src[i];
}

// ---------------------------------------------------------------------------
// seg-mean gather: one wave per destination node; lane owns one float4 slice.
// out[d,:] = (1/max(cnt,1)) * sum_{s in bucket[d]} feat[s,:]
// ---------------------------------------------------------------------------
__global__ __launch_bounds__(256) void seg_mean_gather(
    const float* __restrict__ feat, const int* __restrict__ bucket,
    const int* __restrict__ cnt, int n_dst, float* __restrict__ out)
{
    int d = (int)(((size_t)blockIdx.x * blockDim.x + threadIdx.x) >> 6);
    int lane = threadIdx.x & 63;
    if (d >= n_dst) return;
    int c = cnt[d];
    int cc = min(c, CAP);
    const int* b = bucket + (size_t)d * CAP;
    float4 acc = make_float4(0.f, 0.f, 0.f, 0.f);
    for (int i = 0; i < cc; ++i) {
        int s = b[i];  // broadcast within wave
        float4 v = ((const float4*)(feat + (size_t)s * H))[lane];
        acc.x += v.x; acc.y += v.y; acc.z += v.z; acc.w += v.w;
    }
    float inv = 1.0f / fmaxf((float)c, 1.0f);
    acc.x *= inv; acc.y *= inv; acc.z *= inv; acc.w *= inv;
    ((float4*)(out + (size_t)d * H))[lane] = acc;
}

// ---------------------------------------------------------------------------
// edge dot: out[e] = dot(P[ia[e]], Q[ib[e]]), one wave per edge
// ---------------------------------------------------------------------------
__global__ __launch_bounds__(256) void edge_dot(
    const float* __restrict__ P, const float* __restrict__ Q,
    const int* __restrict__ ia, const int* __restrict__ ib,
    int nE, float* __restrict__ out)
{
    int e = (int)(((size_t)blockIdx.x * blockDim.x + threadIdx.x) >> 6);
    int lane = threadIdx.x & 63;
    if (e >= nE) return;
    float4 a = ((const float4*)(P + (size_t)ia[e] * H))[lane];
    float4 b = ((const float4*)(Q + (size_t)ib[e] * H))[lane];
    float v = a.x * b.x + a.y * b.y + a.z * b.z + a.w * b.w;
#pragma unroll
    for (int off = 32; off; off >>= 1) v += __shfl_down(v, off);
    if (lane == 0) out[e] = v;
}

// ---------------------------------------------------------------------------
// host-side helpers
// ---------------------------------------------------------------------------
static inline void launch_gemm(const float* A, const float* W, const float* bias,
                               float* C, int M, int N, int K,
                               bool accum, bool relu, hipStream_t s)
{
    dim3 grid((M + 63) / 64, N / 64);
    dim3 block(256);
    if (accum) {
        if (relu) gemm_nt<true, true><<<grid, block, 0, s>>>(A, W, bias, C, M, N, K);
        else      gemm_nt<true, false><<<grid, block, 0, s>>>(A, W, bias, C, M, N, K);
    } else {
        if (relu) gemm_nt<false, true><<<grid, block, 0, s>>>(A, W, bias, C, M, N, K);
        else      gemm_nt<false, false><<<grid, block, 0, s>>>(A, W, bias, C, M, N, K);
    }
}

static inline void launch_seg_mean(const float* feat, const int* ei, int E,
                                   int n_dst, float* agg, int* cnt, int* bucket,
                                   hipStream_t s)
{
    // zero the int counters (n_dst ints, 16B multiple since n_dst%4==0)
    fill_zero<<<64, 256, 0, s>>>((float4*)cnt, (size_t)n_dst / 4);
    build_bucket<<<(E + 255) / 256, 256, 0, s>>>(ei, ei + E, E, cnt, bucket);
    seg_mean_gather<<<(n_dst * 64 + 255) / 256, 256, 0, s>>>(feat, bucket, cnt, n_dst, agg);
}

extern "C" void kernel_launch(void* const* d_in, const int* in_sizes, int n_in,
                              void* d_out, int out_size, void* d_ws, size_t ws_size,
                              hipStream_t stream)
{
    const float* x_pep  = (const float*)d_in[0];
    const float* x_prot = (const float*)d_in[1];
    const float* Wpep   = (const float*)d_in[2];
    const float* bpep   = (const float*)d_in[3];
    const float* Wprot  = (const float*)d_in[4];
    const float* bprot  = (const float*)d_in[5];
    const float* Wl1    = (const float*)d_in[6];
    const float* bl1    = (const float*)d_in[7];
    const float* Wr1    = (const float*)d_in[8];
    const float* Wl2    = (const float*)d_in[9];
    const float* bl2    = (const float*)d_in[10];
    const float* Wr2    = (const float*)d_in[11];
    const int* ei_pp    = (const int*)d_in[12];
    const int* ei_rp    = (const int*)d_in[13];
    const int* ei_prot  = (const int*)d_in[14];
    const int* eli_het  = (const int*)d_in[15];
    const int* eli_homo = (const int*)d_in[16];

    const int E   = in_sizes[12] / 2;   // 300000
    const int EL  = in_sizes[15] / 2;   // 200000
    const int FIN = in_sizes[2] / H;    // 1280

    float* out = (float*)d_out;

    // workspace layout:
    //   5 node buffers (50000x256 f32)          = 256.0 MB
    //   cnt   (50000 int)                        = 0.2 MB
    //   bucket(50000 x CAP int)                  = 12.8 MB
    const size_t nodeElems = (size_t)NNODE * H;
    float* bufA = (float*)d_ws;          // h_pep   -> p2
    float* bufB = bufA + nodeElems;      // h_prot  -> q2
    float* bufC = bufB + nodeElems;      // p1
    float* bufD = bufC + nodeElems;      // q1
    float* bufE = bufD + nodeElems;      // seg-mean scratch
    int*   cnt    = (int*)(bufE + nodeElems);
    int*   bucket = cnt + NNODE;

    const size_t HH = (size_t)H * H;

    // --- input projections -------------------------------------------------
    launch_gemm(x_pep,  Wpep,  bpep,  bufA, NNODE, H, FIN, false, false, stream); // h_pep
    launch_gemm(x_prot, Wprot, bprot, bufB, NNODE, H, FIN, false, false, stream); // h_prot

    // --- layer 1: p1 = relu(sage(h_prot -> pep via ei_rp)) ------------------
    launch_seg_mean(bufB, ei_rp, E, NNODE, bufE, cnt, bucket, stream);
    launch_gemm(bufE, Wl1 + 1 * HH, bl1 + 1 * H, bufC, NNODE, H, H, false, false, stream);
    launch_gemm(bufA, Wr1 + 1 * HH, nullptr,     bufC, NNODE, H, H, true,  true,  stream); // relu

    // --- layer 1: q1 = relu(sage(pep->prot, ei_pp) + sage(prot->prot, ei_prot))
    launch_seg_mean(bufA, ei_pp, E, NNODE, bufE, cnt, bucket, stream);
    launch_gemm(bufE, Wl1 + 0 * HH, bl1 + 0 * H, bufD, NNODE, H, H, false, false, stream);
    launch_gemm(bufB, Wr1 + 0 * HH, nullptr,     bufD, NNODE, H, H, true,  false, stream);
    launch_seg_mean(bufB, ei_prot, E, NNODE, bufE, cnt, bucket, stream);
    launch_gemm(bufE, Wl1 + 2 * HH, bl1 + 2 * H, bufD, NNODE, H, H, true,  false, stream);
    launch_gemm(bufB, Wr1 + 2 * HH, nullptr,     bufD, NNODE, H, H, true,  true,  stream); // relu

    // --- layer 2: p2 = sage(q1 -> pep via ei_rp) + p1 @ Wr2[1]^T  (into bufA)
    launch_seg_mean(bufD, ei_rp, E, NNODE, bufE, cnt, bucket, stream);
    launch_gemm(bufE, Wl2 + 1 * HH, bl2 + 1 * H, bufA, NNODE, H, H, false, false, stream);
    launch_gemm(bufC, Wr2 + 1 * HH, nullptr,     bufA, NNODE, H, H, true,  false, stream);

    // --- layer 2: q2 = sage(p1->prot, ei_pp) + sage(q1->prot, ei_prot) (into bufB)
    launch_seg_mean(bufC, ei_pp, E, NNODE, bufE, cnt, bucket, stream);
    launch_gemm(bufE, Wl2 + 0 * HH, bl2 + 0 * H, bufB, NNODE, H, H, false, false, stream);
    launch_gemm(bufD, Wr2 + 0 * HH, nullptr,     bufB, NNODE, H, H, true,  false, stream);
    launch_seg_mean(bufD, ei_prot, E, NNODE, bufE, cnt, bucket, stream);
    launch_gemm(bufE, Wl2 + 2 * HH, bl2 + 2 * H, bufB, NNODE, H, H, true,  false, stream);
    launch_gemm(bufD, Wr2 + 2 * HH, nullptr,     bufB, NNODE, H, H, true,  false, stream);

    // --- edge classifiers ----------------------------------------------------
    edge_dot<<<(EL + 3) / 4, 256, 0, stream>>>(bufA, bufB, eli_het,  eli_het  + EL, EL, out);
    edge_dot<<<(EL + 3) / 4, 256, 0, stream>>>(bufB, bufB, eli_homo, eli_homo + EL, EL, out + EL);
}

// Round 3
// 932.112 us; speedup vs baseline: 9.0241x; 2.8172x over previous
//
#include <hip/hip_runtime.h>

using u16 = unsigned short;
using u32 = unsigned int;

#define H 256
#define NNODE 50000
#define CAP 32        // Poisson(6): P(deg>32) ~ 1e-15 -> safe
#define BM 128
#define BN 128
#define BK 64         // bf16 elems per staged K tile = 128 bytes/row

typedef __attribute__((ext_vector_type(8))) short bf16x8;
typedef __attribute__((ext_vector_type(4))) float f32x4;

struct AChunks { const void* p[5]; };   // each chunk covers 256 k-elems

__device__ __forceinline__ u16 f2b(float f) {        // f32 -> bf16 RNE
    u32 u = __builtin_bit_cast(u32, f);
    return (u16)((u + 0x7FFFu + ((u >> 16) & 1u)) >> 16);
}
__device__ __forceinline__ float b2f(u16 h) {
    u32 u = ((u32)h) << 16;
    return __builtin_bit_cast(float, u);
}
__device__ __forceinline__ void gld_lds16(const void* g, void* l) {
    __builtin_amdgcn_global_load_lds(
        (__attribute__((address_space(1))) void*)(void*)g,
        (__attribute__((address_space(3))) void*)l, 16, 0, 0);
}

// ---------------------------------------------------------------------------
// bf16 MFMA GEMM: C[M,256] = concat_K(A chunks) @ Bw[256,Ktot]^T + bias, opt relu
// 128x128 tile, BK=64, 4 waves (2x2), 16x16x32 MFMA, XOR-swizzled LDS.
// AF32: A chunks are f32 (reg-staged + converted); else bf16 via global_load_lds.
// ---------------------------------------------------------------------------
template<bool AF32, bool RELU>
__global__ __launch_bounds__(256) void gemm_mfma(
    AChunks ac, int aStride, const u16* __restrict__ Bw,
    const float* __restrict__ bias, u16* __restrict__ C, int M, int Ktot)
{
    __shared__ __align__(16) char As[BM * 128];
    __shared__ __align__(16) char Bs[BN * 128];

    const int tid = threadIdx.x;
    const int l  = tid & 63;
    const int w  = tid >> 6;
    const int wr = w >> 1;
    const int wc = w & 1;
    const int m0 = blockIdx.x * BM;
    const int n0 = blockIdx.y * BN;

    f32x4 acc[4][4];
#pragma unroll
    for (int i = 0; i < 4; ++i)
#pragma unroll
        for (int j = 0; j < 4; ++j) acc[i][j] = f32x4{0.f, 0.f, 0.f, 0.f};

    for (int k0 = 0; k0 < Ktot; k0 += BK) {
        const int chunk = k0 >> 8;
        const int kk = k0 & 255;
        // ---- stage B tile [128 cols][64 k] via global_load_lds ----
#pragma unroll
        for (int i = 0; i < 4; ++i) {
            int r = w * 32 + i * 8 + (l >> 3);
            int sb = ((l & 7) * 16) ^ ((r & 7) << 4);      // pre-swizzled source
            const u16* g = Bw + (size_t)(n0 + r) * Ktot + k0 + (sb >> 1);
            gld_lds16(g, Bs + r * 128);
        }
        // ---- stage A tile ----
        if (!AF32) {
            const u16* base = (const u16*)ac.p[chunk];
#pragma unroll
            for (int i = 0; i < 4; ++i) {
                int r = w * 32 + i * 8 + (l >> 3);
                int row = m0 + r; row = row < M ? row : M - 1;
                int sb = ((l & 7) * 16) ^ ((r & 7) << 4);
                const u16* g = base + (size_t)row * aStride + kk + (sb >> 1);
                gld_lds16(g, As + r * 128);
            }
        } else {
            const float* base = (const float*)ac.p[chunk];
#pragma unroll
            for (int i = 0; i < 8; ++i) {
                int r = w * 32 + i * 4 + (l >> 4);
                int row = m0 + r; row = row < M ? row : M - 1;
                float4 v = *(const float4*)(base + (size_t)row * aStride + kk + (l & 15) * 4);
                ushort4 hh;
                hh.x = f2b(v.x); hh.y = f2b(v.y); hh.z = f2b(v.z); hh.w = f2b(v.w);
                int db = ((l & 15) * 8) ^ ((r & 7) << 4);
                *(ushort4*)(As + r * 128 + db) = hh;
            }
        }
        __syncthreads();
        // ---- compute: 2 k-slices x 16 MFMA ----
#pragma unroll
        for (int ks = 0; ks < 2; ++ks) {
            bf16x8 af[4], bfr[4];
#pragma unroll
            for (int mi = 0; mi < 4; ++mi) {
                int r = wr * 64 + mi * 16 + (l & 15);
                int off = (ks * 64 + (l >> 4) * 16) ^ ((r & 7) << 4);
                af[mi] = *(const bf16x8*)(As + r * 128 + off);
            }
#pragma unroll
            for (int ni = 0; ni < 4; ++ni) {
                int r = wc * 64 + ni * 16 + (l & 15);
                int off = (ks * 64 + (l >> 4) * 16) ^ ((r & 7) << 4);
                bfr[ni] = *(const bf16x8*)(Bs + r * 128 + off);
            }
#pragma unroll
            for (int mi = 0; mi < 4; ++mi)
#pragma unroll
                for (int ni = 0; ni < 4; ++ni)
                    acc[mi][ni] = __builtin_amdgcn_mfma_f32_16x16x32_bf16(
                        af[mi], bfr[ni], acc[mi][ni], 0, 0, 0);
        }
        __syncthreads();
    }
    // ---- epilogue: C/D layout col=lane&15, row=(lane>>4)*4+reg ----
    const int fr = l & 15, fq = l >> 4;
#pragma unroll
    for (int ni = 0; ni < 4; ++ni) {
        int col = n0 + wc * 64 + ni * 16 + fr;
        float bv = bias ? bias[col] : 0.f;
#pragma unroll
        for (int mi = 0; mi < 4; ++mi) {
            int rowb = m0 + wr * 64 + mi * 16 + fq * 4;
#pragma unroll
            for (int j = 0; j < 4; ++j) {
                int row = rowb + j;
                if (row < M) {
                    float v = acc[mi][ni][j] + bv;
                    if (RELU) v = fmaxf(v, 0.f);
                    C[(size_t)row * H + col] = f2b(v);
                }
            }
        }
    }
}

// ---------------------------------------------------------------------------
// small utility kernels
// ---------------------------------------------------------------------------
__global__ __launch_bounds__(256) void fill_zero(float4* __restrict__ p, size_t n4)
{
    size_t i = (size_t)blockIdx.x * blockDim.x + threadIdx.x;
    size_t stride = (size_t)gridDim.x * blockDim.x;
    for (; i < n4; i += stride) p[i] = make_float4(0.f, 0.f, 0.f, 0.f);
}

__global__ __launch_bounds__(256) void build_bucket(
    const int* __restrict__ src, const int* __restrict__ dst, int nE,
    int* __restrict__ cnt, int* __restrict__ bucket)
{
    int i = blockIdx.x * blockDim.x + threadIdx.x;
    if (i >= nE) return;
    int d = dst[i];
    int pos = atomicAdd(&cnt[d], 1);
    if (pos < CAP) bucket[(size_t)d * CAP + pos] = src[i];
}

__global__ __launch_bounds__(256) void seg_mean_gather(
    const u16* __restrict__ feat, const int* __restrict__ bucket,
    const int* __restrict__ cnt, int n_dst, u16* __restrict__ out)
{
    int d = (int)(((size_t)blockIdx.x * blockDim.x + threadIdx.x) >> 6);
    int lane = threadIdx.x & 63;
    if (d >= n_dst) return;
    int c = cnt[d];
    int cc = c < CAP ? c : CAP;
    const int* b = bucket + (size_t)d * CAP;
    float a0 = 0.f, a1 = 0.f, a2 = 0.f, a3 = 0.f;
    for (int i = 0; i < cc; ++i) {
        int s = b[i];
        uint2 v = *(const uint2*)(feat + (size_t)s * H + lane * 4);
        a0 += b2f((u16)(v.x & 0xffff));
        a1 += b2f((u16)(v.x >> 16));
        a2 += b2f((u16)(v.y & 0xffff));
        a3 += b2f((u16)(v.y >> 16));
    }
    float inv = 1.0f / fmaxf((float)c, 1.0f);
    uint2 o;
    o.x = (u32)f2b(a0 * inv) | ((u32)f2b(a1 * inv) << 16);
    o.y = (u32)f2b(a2 * inv) | ((u32)f2b(a3 * inv) << 16);
    *(uint2*)(out + (size_t)d * H + lane * 4) = o;
}

__global__ __launch_bounds__(256) void edge_dot(
    const u16* __restrict__ P, const u16* __restrict__ Q,
    const int* __restrict__ ia, const int* __restrict__ ib,
    int nE, float* __restrict__ out)
{
    int e = (int)(((size_t)blockIdx.x * blockDim.x + threadIdx.x) >> 6);
    int lane = threadIdx.x & 63;
    if (e >= nE) return;
    uint2 a = *(const uint2*)(P + (size_t)ia[e] * H + lane * 4);
    uint2 b = *(const uint2*)(Q + (size_t)ib[e] * H + lane * 4);
    float v = b2f((u16)(a.x & 0xffff)) * b2f((u16)(b.x & 0xffff))
            + b2f((u16)(a.x >> 16))    * b2f((u16)(b.x >> 16))
            + b2f((u16)(a.y & 0xffff)) * b2f((u16)(b.y & 0xffff))
            + b2f((u16)(a.y >> 16))    * b2f((u16)(b.y >> 16));
#pragma unroll
    for (int off = 32; off; off >>= 1) v += __shfl_down(v, off);
    if (lane == 0) out[e] = v;
}

// dst[n*Kdst + koff + k] = bf16(s1[n*Ks+k] (+ s2[n*Ks+k]))
__global__ __launch_bounds__(256) void pack_w(
    const float* __restrict__ s1, const float* __restrict__ s2,
    u16* __restrict__ dst, int Ks, int Kdst, int koff)
{
    int idx = blockIdx.x * blockDim.x + threadIdx.x;
    if (idx >= 256 * Ks) return;
    int n = idx / Ks, k = idx - n * Ks;
    float v = s1[idx];
    if (s2) v += s2[idx];
    dst[(size_t)n * Kdst + koff + k] = f2b(v);
}

__global__ void bias_add2(const float* __restrict__ a, const float* __restrict__ b,
                          float* __restrict__ o)
{
    int i = threadIdx.x;
    o[i] = a[i] + b[i];
}

// ---------------------------------------------------------------------------
// host-side helpers
// ---------------------------------------------------------------------------
static inline void launch_gemm3(const void* a0, const void* a1, const void* a2,
                                const u16* Bw, const float* bias, u16* C,
                                int Ktot, bool relu, hipStream_t s)
{
    AChunks ac = {{a0, a1, a2, nullptr, nullptr}};
    dim3 grid((NNODE + BM - 1) / BM, H / BN);
    if (relu) gemm_mfma<false, true><<<grid, 256, 0, s>>>(ac, 256, Bw, bias, C, NNODE, Ktot);
    else      gemm_mfma<false, false><<<grid, 256, 0, s>>>(ac, 256, Bw, bias, C, NNODE, Ktot);
}

static inline void launch_seg_mean(const u16* feat, const int* ei, int E,
                                   u16* outb, int* cnt, int* bucket, hipStream_t s)
{
    fill_zero<<<64, 256, 0, s>>>((float4*)cnt, NNODE / 4);
    build_bucket<<<(E + 255) / 256, 256, 0, s>>>(ei, ei + E, E, cnt, bucket);
    seg_mean_gather<<<(NNODE * 64 + 255) / 256, 256, 0, s>>>(feat, bucket, cnt, NNODE, outb);
}

extern "C" void kernel_launch(void* const* d_in, const int* in_sizes, int n_in,
                              void* d_out, int out_size, void* d_ws, size_t ws_size,
                              hipStream_t stream)
{
    const float* x_pep  = (const float*)d_in[0];
    const float* x_prot = (const float*)d_in[1];
    const float* Wpep   = (const float*)d_in[2];
    const float* bpep   = (const float*)d_in[3];
    const float* Wprot  = (const float*)d_in[4];
    const float* bprot  = (const float*)d_in[5];
    const float* Wl1    = (const float*)d_in[6];
    const float* bl1    = (const float*)d_in[7];
    const float* Wr1    = (const float*)d_in[8];
    const float* Wl2    = (const float*)d_in[9];
    const float* bl2    = (const float*)d_in[10];
    const float* Wr2    = (const float*)d_in[11];
    const int* ei_pp    = (const int*)d_in[12];
    const int* ei_rp    = (const int*)d_in[13];
    const int* ei_prot  = (const int*)d_in[14];
    const int* eli_het  = (const int*)d_in[15];
    const int* eli_homo = (const int*)d_in[16];

    const int E  = in_sizes[12] / 2;   // 300000
    const int EL = in_sizes[15] / 2;   // 200000
    const int FIN = in_sizes[2] / H;   // 1280

    float* out = (float*)d_out;

    // ---- workspace carve (~163 MB) ----
    const size_t nodeElems = (size_t)NNODE * H;      // bf16 elems
    u16* bufA = (u16*)d_ws;            // h_pep  -> p2
    u16* bufB = bufA + nodeElems;      // h_prot -> q2
    u16* bufC = bufB + nodeElems;      // p1
    u16* bufD = bufC + nodeElems;      // q1
    u16* bufE = bufD + nodeElems;      // mean scratch 1
    u16* bufF = bufE + nodeElems;      // mean scratch 2
    int* cnt    = (int*)(bufF + nodeElems);
    int* bucket = cnt + NNODE;
    u16* Bpep  = (u16*)(bucket + (size_t)NNODE * CAP);
    u16* Bprot = Bpep  + (size_t)256 * 1280;
    u16* Bp1   = Bprot + (size_t)256 * 1280;
    u16* Bq1   = Bp1   + (size_t)256 * 512;
    u16* Bp2   = Bq1   + (size_t)256 * 768;
    u16* Bq2   = Bp2   + (size_t)256 * 512;
    float* bq1 = (float*)(Bq2 + (size_t)256 * 768);
    float* bq2 = bq1 + 256;

    const size_t HH = (size_t)H * H;

    // ---- weight/bias prep (bf16 concat B matrices) ----
    int gW = (256 * 1280 + 255) / 256, gH = (65536 + 255) / 256;
    pack_w<<<gW, 256, 0, stream>>>(Wpep,  nullptr, Bpep,  1280, 1280, 0);
    pack_w<<<gW, 256, 0, stream>>>(Wprot, nullptr, Bprot, 1280, 1280, 0);
    pack_w<<<gH, 256, 0, stream>>>(Wl1 + 1 * HH, nullptr,       Bp1, 256, 512, 0);
    pack_w<<<gH, 256, 0, stream>>>(Wr1 + 1 * HH, nullptr,       Bp1, 256, 512, 256);
    pack_w<<<gH, 256, 0, stream>>>(Wl1 + 0 * HH, nullptr,       Bq1, 256, 768, 0);
    pack_w<<<gH, 256, 0, stream>>>(Wl1 + 2 * HH, nullptr,       Bq1, 256, 768, 256);
    pack_w<<<gH, 256, 0, stream>>>(Wr1 + 0 * HH, Wr1 + 2 * HH,  Bq1, 256, 768, 512);
    pack_w<<<gH, 256, 0, stream>>>(Wl2 + 1 * HH, nullptr,       Bp2, 256, 512, 0);
    pack_w<<<gH, 256, 0, stream>>>(Wr2 + 1 * HH, nullptr,       Bp2, 256, 512, 256);
    pack_w<<<gH, 256, 0, stream>>>(Wl2 + 0 * HH, nullptr,       Bq2, 256, 768, 0);
    pack_w<<<gH, 256, 0, stream>>>(Wl2 + 2 * HH, nullptr,       Bq2, 256, 768, 256);
    pack_w<<<gH, 256, 0, stream>>>(Wr2 + 0 * HH, Wr2 + 2 * HH,  Bq2, 256, 768, 512);
    bias_add2<<<1, 256, 0, stream>>>(bl1, bl1 + 512, bq1);
    bias_add2<<<1, 256, 0, stream>>>(bl2, bl2 + 512, bq2);

    // ---- input projections (f32 A, reg-staged bf16 conversion) ----
    {
        dim3 grid((NNODE + BM - 1) / BM, H / BN);
        AChunks ap = {{x_pep, x_pep + 256, x_pep + 512, x_pep + 768, x_pep + 1024}};
        gemm_mfma<true, false><<<grid, 256, 0, stream>>>(ap, FIN, Bpep, bpep, bufA, NNODE, FIN);
        AChunks aq = {{x_prot, x_prot + 256, x_prot + 512, x_prot + 768, x_prot + 1024}};
        gemm_mfma<true, false><<<grid, 256, 0, stream>>>(aq, FIN, Bprot, bprot, bufB, NNODE, FIN);
    }

    // ---- layer 1 ----
    // p1 = relu([mean_rp(h_prot) | h_pep] @ [Wl1_1|Wr1_1]^T + bl1_1)
    launch_seg_mean(bufB, ei_rp, E, bufE, cnt, bucket, stream);
    launch_gemm3(bufE, bufA, nullptr, Bp1, bl1 + 256, bufC, 512, true, stream);
    // q1 = relu([mean_pp(h_pep) | mean_prot(h_prot) | h_prot] @ [Wl1_0|Wl1_2|Wr1_0+Wr1_2]^T + bl1_0+bl1_2)
    launch_seg_mean(bufA, ei_pp, E, bufE, cnt, bucket, stream);
    launch_seg_mean(bufB, ei_prot, E, bufF, cnt, bucket, stream);
    launch_gemm3(bufE, bufF, bufB, Bq1, bq1, bufD, 768, true, stream);

    // ---- layer 2 ----
    // p2 = [mean_rp(q1) | p1] @ [Wl2_1|Wr2_1]^T + bl2_1   (into bufA)
    launch_seg_mean(bufD, ei_rp, E, bufE, cnt, bucket, stream);
    launch_gemm3(bufE, bufC, nullptr, Bp2, bl2 + 256, bufA, 512, false, stream);
    // q2 = [mean_pp(p1) | mean_prot(q1) | q1] @ [Wl2_0|Wl2_2|Wr2_0+Wr2_2]^T + bl2_0+bl2_2 (into bufB)
    launch_seg_mean(bufC, ei_pp, E, bufE, cnt, bucket, stream);
    launch_seg_mean(bufD, ei_prot, E, bufF, cnt, bucket, stream);
    launch_gemm3(bufE, bufF, bufD, Bq2, bq2, bufB, 768, false, stream);

    // ---- edge classifiers ----
    edge_dot<<<(EL + 3) / 4, 256, 0, stream>>>(bufA, bufB, eli_het,  eli_het  + EL, EL, out);
    edge_dot<<<(EL + 3) / 4, 256, 0, stream>>>(bufB, bufB, eli_homo, eli_homo + EL, EL, out + EL);
}

// Round 4
// 699.344 us; speedup vs baseline: 12.0277x; 1.3328x over previous
//
#include <hip/hip_runtime.h>

using u16 = unsigned short;
using u32 = unsigned int;

#define H 256
#define NNODE 50000
#define CAP 32        // Poisson(6): P(deg>32) ~ 1e-15
#define BM 128
#define BN 128
#define BK 64         // bf16 elems per K tile = 128 bytes/row

typedef __attribute__((ext_vector_type(8))) short bf16x8;
typedef __attribute__((ext_vector_type(4))) float f32x4;

struct AChunks { const void* p[3]; };

__device__ __forceinline__ u16 f2b(float f) {        // f32 -> bf16 RNE
    u32 u = __builtin_bit_cast(u32, f);
    return (u16)((u + 0x7FFFu + ((u >> 16) & 1u)) >> 16);
}
__device__ __forceinline__ float b2f(u16 h) {
    u32 u = ((u32)h) << 16;
    return __builtin_bit_cast(float, u);
}
__device__ __forceinline__ void gld_lds16(const void* g, void* l) {
    __builtin_amdgcn_global_load_lds(
        (__attribute__((address_space(1))) void*)(void*)g,
        (__attribute__((address_space(3))) void*)l, 16, 0, 0);
}
__device__ __forceinline__ u32 packbf(float a, float b) {
    return (u32)f2b(a) | ((u32)f2b(b) << 16);
}

// ---------------------------------------------------------------------------
// Pipelined bf16 MFMA GEMM: C[M,256] = concat_K(A) @ Bw[256,Ktot]^T + bias
// 128x128 tile, BK=64, 512 threads (8 waves, 2m x 4n), dbuf LDS,
// 2-tile-deep prefetch with counted vmcnt, raw s_barrier.
// AF32: A is f32, reg-staged + converted (T14 split). Else bf16 via gld_lds.
// ---------------------------------------------------------------------------
template<bool AF32, bool RELU>
__global__ __launch_bounds__(512) void gemm_pipe(
    AChunks ac, int aStride, const u16* __restrict__ Bw,
    const float* __restrict__ bias, u16* __restrict__ C, int M, int Ktot)
{
    __shared__ __align__(16) char As[2][BM * 128];
    __shared__ __align__(16) char Bs[2][BN * 128];

    const int tid = threadIdx.x;
    const int l   = tid & 63;
    const int w   = tid >> 6;          // 0..7
    const int wr  = w >> 2, wc = w & 3;
    const int m0  = blockIdx.x * BM;
    const int n0  = blockIdx.y * BN;
    const int nk  = Ktot >> 6;

    f32x4 acc[4][2];
#pragma unroll
    for (int i = 0; i < 4; ++i)
#pragma unroll
        for (int j = 0; j < 2; ++j) acc[i][j] = f32x4{0.f, 0.f, 0.f, 0.f};

    auto stageB = [&](int k, int bi) {
        int k0 = k * 64;
#pragma unroll
        for (int i = 0; i < 2; ++i) {
            int ci = i * 512 + tid;
            int r = ci >> 3, c16 = ci & 7;
            int sb = (c16 * 16) ^ ((r & 7) << 4);      // pre-swizzled source
            const u16* g = Bw + (size_t)(n0 + r) * Ktot + k0 + (sb >> 1);
            gld_lds16(g, &Bs[bi][ci * 16]);
        }
    };
    auto stageAb = [&](int k, int bi) {
        int k0 = k * 64;
        const u16* base = (const u16*)ac.p[k0 >> 8];
        int kk = k0 & 255;
#pragma unroll
        for (int i = 0; i < 2; ++i) {
            int ci = i * 512 + tid;
            int r = ci >> 3, c16 = ci & 7;
            int row = m0 + r; row = row < M ? row : M - 1;
            int sb = (c16 * 16) ^ ((r & 7) << 4);
            const u16* g = base + (size_t)row * aStride + kk + (sb >> 1);
            gld_lds16(g, &As[bi][ci * 16]);
        }
    };
    auto loadAf = [&](int k, float4 (&rA)[4]) {
        int k0 = k * 64;
        const float* base = (const float*)ac.p[0];
        int r = tid >> 2;
        int row = m0 + r; row = row < M ? row : M - 1;
        const float* g = base + (size_t)row * aStride + k0 + (tid & 3) * 16;
#pragma unroll
        for (int j = 0; j < 4; ++j) rA[j] = *(const float4*)(g + j * 4);
    };
    auto writeAf = [&](float4 (&rA)[4], int bi) {
        int r  = tid >> 2;
        int cb = (tid & 3) * 32;
        int sw = (r & 7) << 4;
        uint4 lo, hi;
        lo.x = packbf(rA[0].x, rA[0].y); lo.y = packbf(rA[0].z, rA[0].w);
        lo.z = packbf(rA[1].x, rA[1].y); lo.w = packbf(rA[1].z, rA[1].w);
        hi.x = packbf(rA[2].x, rA[2].y); hi.y = packbf(rA[2].z, rA[2].w);
        hi.z = packbf(rA[3].x, rA[3].y); hi.w = packbf(rA[3].z, rA[3].w);
        *(uint4*)&As[bi][r * 128 + (cb ^ sw)]        = lo;
        *(uint4*)&As[bi][r * 128 + ((cb + 16) ^ sw)] = hi;
    };
    auto compute = [&](int bi) {
#pragma unroll
        for (int ks = 0; ks < 2; ++ks) {
            bf16x8 af[4], bfr[2];
#pragma unroll
            for (int mi = 0; mi < 4; ++mi) {
                int r = wr * 64 + mi * 16 + (l & 15);
                int off = (ks * 64 + (l >> 4) * 16) ^ ((r & 7) << 4);
                af[mi] = *(const bf16x8*)&As[bi][r * 128 + off];
            }
#pragma unroll
            for (int ni = 0; ni < 2; ++ni) {
                int r = wc * 32 + ni * 16 + (l & 15);
                int off = (ks * 64 + (l >> 4) * 16) ^ ((r & 7) << 4);
                bfr[ni] = *(const bf16x8*)&Bs[bi][r * 128 + off];
            }
#pragma unroll
            for (int mi = 0; mi < 4; ++mi)
#pragma unroll
                for (int ni = 0; ni < 2; ++ni)
                    acc[mi][ni] = __builtin_amdgcn_mfma_f32_16x16x32_bf16(
                        af[mi], bfr[ni], acc[mi][ni], 0, 0, 0);
        }
    };
    auto body = [&](int k, float4 (&rA)[4], int cur) {
        if (AF32) {
            asm volatile("s_waitcnt vmcnt(6)" ::: "memory");   // set(k) done
            writeAf(rA, cur);
            asm volatile("s_waitcnt lgkmcnt(0)" ::: "memory"); // ds_writes visible
        } else {
            asm volatile("s_waitcnt vmcnt(4)" ::: "memory");   // set(k) done
        }
        __builtin_amdgcn_sched_barrier(0);
        __builtin_amdgcn_s_barrier();
        __builtin_amdgcn_sched_barrier(0);
        compute(cur);
        __builtin_amdgcn_sched_barrier(0);
        __builtin_amdgcn_s_barrier();
        __builtin_amdgcn_sched_barrier(0);
        int kq = k + 2; if (kq > nk - 1) kq = nk - 1;  // clamped dup keeps count
        stageB(kq, cur);
        __builtin_amdgcn_sched_barrier(0);
        if (AF32) loadAf(kq, rA);
        else      stageAb(kq, cur);
        __builtin_amdgcn_sched_barrier(0);
    };

    float4 rA0[4], rA1[4];
    if (AF32) {
        stageB(0, 0); __builtin_amdgcn_sched_barrier(0);
        loadAf(0, rA0); __builtin_amdgcn_sched_barrier(0);
        stageB(1, 1); __builtin_amdgcn_sched_barrier(0);
        loadAf(1, rA1); __builtin_amdgcn_sched_barrier(0);
    } else {
        stageB(0, 0); stageAb(0, 0);
        __builtin_amdgcn_sched_barrier(0);
        stageB(1, 1); stageAb(1, 1);
        __builtin_amdgcn_sched_barrier(0);
    }
    for (int k = 0; k < nk; k += 2) {   // nk even for all our shapes
        body(k,     rA0, 0);
        body(k + 1, rA1, 1);
    }

    // epilogue: C/D layout col=lane&15, row=(lane>>4)*4+reg
    const int fr = l & 15, fq = l >> 4;
#pragma unroll
    for (int ni = 0; ni < 2; ++ni) {
        int col = n0 + wc * 32 + ni * 16 + fr;
        float bv = bias ? bias[col] : 0.f;
#pragma unroll
        for (int mi = 0; mi < 4; ++mi) {
            int rowb = m0 + wr * 64 + mi * 16 + fq * 4;
#pragma unroll
            for (int j = 0; j < 4; ++j) {
                int row = rowb + j;
                if (row < M) {
                    float v = acc[mi][ni][j] + bv;
                    if (RELU) v = fmaxf(v, 0.f);
                    C[(size_t)row * H + col] = f2b(v);
                }
            }
        }
    }
}

// ---------------------------------------------------------------------------
// utility kernels
// ---------------------------------------------------------------------------
__global__ __launch_bounds__(256) void fill_zero(float4* __restrict__ p, size_t n4)
{
    size_t i = (size_t)blockIdx.x * blockDim.x + threadIdx.x;
    size_t stride = (size_t)gridDim.x * blockDim.x;
    for (; i < n4; i += stride) p[i] = make_float4(0.f, 0.f, 0.f, 0.f);
}

__global__ __launch_bounds__(256) void build_bucket(
    const int* __restrict__ src, const int* __restrict__ dst, int nE,
    int* __restrict__ cnt, int* __restrict__ bucket)
{
    int i = blockIdx.x * blockDim.x + threadIdx.x;
    if (i >= nE) return;
    int d = dst[i];
    int pos = atomicAdd(&cnt[d], 1);
    if (pos < CAP) bucket[(size_t)d * CAP + pos] = src[i];
}

__global__ __launch_bounds__(256) void seg_mean_gather(
    const u16* __restrict__ feat, const int* __restrict__ bucket,
    const int* __restrict__ cnt, int n_dst, u16* __restrict__ out)
{
    int d = (int)(((size_t)blockIdx.x * blockDim.x + threadIdx.x) >> 6);
    int lane = threadIdx.x & 63;
    if (d >= n_dst) return;
    int c = cnt[d];
    int cc = c < CAP ? c : CAP;
    const int* b = bucket + (size_t)d * CAP;
    float a0 = 0.f, a1 = 0.f, a2 = 0.f, a3 = 0.f;
    int i = 0;
    for (; i + 4 <= cc; i += 4) {            // unroll-4: 4 gathers in flight
        int s0 = b[i], s1 = b[i + 1], s2 = b[i + 2], s3 = b[i + 3];
        uint2 v0 = *(const uint2*)(feat + (size_t)s0 * H + lane * 4);
        uint2 v1 = *(const uint2*)(feat + (size_t)s1 * H + lane * 4);
        uint2 v2 = *(const uint2*)(feat + (size_t)s2 * H + lane * 4);
        uint2 v3 = *(const uint2*)(feat + (size_t)s3 * H + lane * 4);
        a0 += b2f((u16)(v0.x & 0xffff)) + b2f((u16)(v1.x & 0xffff))
            + b2f((u16)(v2.x & 0xffff)) + b2f((u16)(v3.x & 0xffff));
        a1 += b2f((u16)(v0.x >> 16)) + b2f((u16)(v1.x >> 16))
            + b2f((u16)(v2.x >> 16)) + b2f((u16)(v3.x >> 16));
        a2 += b2f((u16)(v0.y & 0xffff)) + b2f((u16)(v1.y & 0xffff))
            + b2f((u16)(v2.y & 0xffff)) + b2f((u16)(v3.y & 0xffff));
        a3 += b2f((u16)(v0.y >> 16)) + b2f((u16)(v1.y >> 16))
            + b2f((u16)(v2.y >> 16)) + b2f((u16)(v3.y >> 16));
    }
    for (; i < cc; ++i) {
        uint2 v = *(const uint2*)(feat + (size_t)b[i] * H + lane * 4);
        a0 += b2f((u16)(v.x & 0xffff));
        a1 += b2f((u16)(v.x >> 16));
        a2 += b2f((u16)(v.y & 0xffff));
        a3 += b2f((u16)(v.y >> 16));
    }
    float inv = 1.0f / fmaxf((float)c, 1.0f);
    uint2 o;
    o.x = packbf(a0 * inv, a1 * inv);
    o.y = packbf(a2 * inv, a3 * inv);
    *(uint2*)(out + (size_t)d * H + lane * 4) = o;
}

// 2 edges per wave: 32 lanes x 16B per edge row
__global__ __launch_bounds__(256) void edge_dot(
    const u16* __restrict__ P, const u16* __restrict__ Q,
    const int* __restrict__ ia, const int* __restrict__ ib,
    int nE, float* __restrict__ out)
{
    int gi = blockIdx.x * 256 + threadIdx.x;
    int e = gi >> 5, l32 = gi & 31;
    if (e >= nE) return;
    uint4 a = *(const uint4*)(P + (size_t)ia[e] * H + l32 * 8);
    uint4 b = *(const uint4*)(Q + (size_t)ib[e] * H + l32 * 8);
    float v = 0.f;
    v += b2f((u16)(a.x & 0xffff)) * b2f((u16)(b.x & 0xffff));
    v += b2f((u16)(a.x >> 16))    * b2f((u16)(b.x >> 16));
    v += b2f((u16)(a.y & 0xffff)) * b2f((u16)(b.y & 0xffff));
    v += b2f((u16)(a.y >> 16))    * b2f((u16)(b.y >> 16));
    v += b2f((u16)(a.z & 0xffff)) * b2f((u16)(b.z & 0xffff));
    v += b2f((u16)(a.z >> 16))    * b2f((u16)(b.z >> 16));
    v += b2f((u16)(a.w & 0xffff)) * b2f((u16)(b.w & 0xffff));
    v += b2f((u16)(a.w >> 16))    * b2f((u16)(b.w >> 16));
#pragma unroll
    for (int off = 16; off; off >>= 1) v += __shfl_xor(v, off);
    if (l32 == 0) out[e] = v;
}

// fused weight pack: 12 items, 1024 elems per block
struct PackTab {
    const float* s1[12]; const float* s2[12]; u16* dst[12];
    int Ks[12], Kdst[12], koff[12], blk0[13];
};
__global__ __launch_bounds__(256) void pack_all(PackTab t)
{
    int b = blockIdx.x;
    int it = 0;
    while (it < 11 && b >= t.blk0[it + 1]) ++it;
    int idx = (b - t.blk0[it]) * 1024 + threadIdx.x * 4;
    int Ks = t.Ks[it];
    if (idx >= 256 * Ks) return;
    int n = idx / Ks;
    int k = idx - n * Ks;
    float4 v = *(const float4*)(t.s1[it] + idx);
    if (t.s2[it]) {
        float4 u = *(const float4*)(t.s2[it] + idx);
        v.x += u.x; v.y += u.y; v.z += u.z; v.w += u.w;
    }
    ushort4 h;
    h.x = f2b(v.x); h.y = f2b(v.y); h.z = f2b(v.z); h.w = f2b(v.w);
    *(ushort4*)(t.dst[it] + (size_t)n * t.Kdst[it] + t.koff[it] + k) = h;
}

__global__ void bias_pair(const float* __restrict__ bl1, const float* __restrict__ bl2,
                          float* __restrict__ bq1, float* __restrict__ bq2)
{
    int i = threadIdx.x;
    if (blockIdx.x == 0) bq1[i] = bl1[i] + bl1[512 + i];
    else                 bq2[i] = bl2[i] + bl2[512 + i];
}

// ---------------------------------------------------------------------------
// host-side helpers
// ---------------------------------------------------------------------------
static inline void launch_gemm3(const void* a0, const void* a1, const void* a2,
                                const u16* Bw, const float* bias, u16* C,
                                int Ktot, bool relu, hipStream_t s)
{
    AChunks ac = {{a0, a1, a2}};
    dim3 grid((NNODE + BM - 1) / BM, H / BN);
    if (relu) gemm_pipe<false, true><<<grid, 512, 0, s>>>(ac, 256, Bw, bias, C, NNODE, Ktot);
    else      gemm_pipe<false, false><<<grid, 512, 0, s>>>(ac, 256, Bw, bias, C, NNODE, Ktot);
}

extern "C" void kernel_launch(void* const* d_in, const int* in_sizes, int n_in,
                              void* d_out, int out_size, void* d_ws, size_t ws_size,
                              hipStream_t stream)
{
    const float* x_pep  = (const float*)d_in[0];
    const float* x_prot = (const float*)d_in[1];
    const float* Wpep   = (const float*)d_in[2];
    const float* bpep   = (const float*)d_in[3];
    const float* Wprot  = (const float*)d_in[4];
    const float* bprot  = (const float*)d_in[5];
    const float* Wl1    = (const float*)d_in[6];
    const float* bl1    = (const float*)d_in[7];
    const float* Wr1    = (const float*)d_in[8];
    const float* Wl2    = (const float*)d_in[9];
    const float* bl2    = (const float*)d_in[10];
    const float* Wr2    = (const float*)d_in[11];
    const int* ei_pp    = (const int*)d_in[12];
    const int* ei_rp    = (const int*)d_in[13];
    const int* ei_prot  = (const int*)d_in[14];
    const int* eli_het  = (const int*)d_in[15];
    const int* eli_homo = (const int*)d_in[16];

    const int E  = in_sizes[12] / 2;   // 300000
    const int EL = in_sizes[15] / 2;   // 200000
    const int FIN = in_sizes[2] / H;   // 1280

    float* out = (float*)d_out;

    // ---- workspace carve (~177 MB) ----
    const size_t nodeElems = (size_t)NNODE * H;      // bf16 elems
    u16* bufA = (u16*)d_ws;            // h_pep  -> p2
    u16* bufB = bufA + nodeElems;      // h_prot -> q2
    u16* bufC = bufB + nodeElems;      // p1
    u16* bufD = bufC + nodeElems;      // q1
    u16* bufE = bufD + nodeElems;      // mean scratch 1
    u16* bufF = bufE + nodeElems;      // mean scratch 2
    u16* Bpep  = bufF + nodeElems;
    u16* Bprot = Bpep  + (size_t)256 * 1280;
    u16* Bp1   = Bprot + (size_t)256 * 1280;
    u16* Bq1   = Bp1   + (size_t)256 * 512;
    u16* Bp2   = Bq1   + (size_t)256 * 768;
    u16* Bq2   = Bp2   + (size_t)256 * 512;
    float* bq1 = (float*)(Bq2 + (size_t)256 * 768);
    float* bq2 = bq1 + 256;
    int* cntRP   = (int*)(bq2 + 256);
    int* cntPP   = cntRP + NNODE;
    int* cntPR   = cntPP + NNODE;
    int* bktRP   = cntPR + NNODE;
    int* bktPP   = bktRP + (size_t)NNODE * CAP;
    int* bktPR   = bktPP + (size_t)NNODE * CAP;

    const size_t HH = (size_t)H * H;

    // ---- fused weight pack ----
    PackTab t{};
    int blk = 0, it = 0;
    auto add = [&](const float* s1, const float* s2, u16* d, int Ks, int Kd, int ko) {
        t.s1[it] = s1; t.s2[it] = s2; t.dst[it] = d;
        t.Ks[it] = Ks; t.Kdst[it] = Kd; t.koff[it] = ko;
        t.blk0[it] = blk; blk += (256 * Ks) / 1024; ++it;
    };
    add(Wpep,  nullptr, Bpep,  1280, 1280, 0);
    add(Wprot, nullptr, Bprot, 1280, 1280, 0);
    add(Wl1 + 1 * HH, nullptr,      Bp1, 256, 512, 0);
    add(Wr1 + 1 * HH, nullptr,      Bp1, 256, 512, 256);
    add(Wl1 + 0 * HH, nullptr,      Bq1, 256, 768, 0);
    add(Wl1 + 2 * HH, nullptr,      Bq1, 256, 768, 256);
    add(Wr1 + 0 * HH, Wr1 + 2 * HH, Bq1, 256, 768, 512);
    add(Wl2 + 1 * HH, nullptr,      Bp2, 256, 512, 0);
    add(Wr2 + 1 * HH, nullptr,      Bp2, 256, 512, 256);
    add(Wl2 + 0 * HH, nullptr,      Bq2, 256, 768, 0);
    add(Wl2 + 2 * HH, nullptr,      Bq2, 256, 768, 256);
    add(Wr2 + 0 * HH, Wr2 + 2 * HH, Bq2, 256, 768, 512);
    t.blk0[12] = blk;
    pack_all<<<blk, 256, 0, stream>>>(t);
    bias_pair<<<2, 256, 0, stream>>>(bl1, bl2, bq1, bq2);

    // ---- buckets: built ONCE per edge type, reused by both layers ----
    fill_zero<<<147, 256, 0, stream>>>((float4*)cntRP, (size_t)3 * NNODE / 4);
    build_bucket<<<(E + 255) / 256, 256, 0, stream>>>(ei_rp,   ei_rp + E,   E, cntRP, bktRP);
    build_bucket<<<(E + 255) / 256, 256, 0, stream>>>(ei_pp,   ei_pp + E,   E, cntPP, bktPP);
    build_bucket<<<(E + 255) / 256, 256, 0, stream>>>(ei_prot, ei_prot + E, E, cntPR, bktPR);

    // ---- input projections (f32 A, pipelined) ----
    {
        dim3 grid((NNODE + BM - 1) / BM, H / BN);
        AChunks ap = {{x_pep, nullptr, nullptr}};
        gemm_pipe<true, false><<<grid, 512, 0, stream>>>(ap, FIN, Bpep, bpep, bufA, NNODE, FIN);
        AChunks aq = {{x_prot, nullptr, nullptr}};
        gemm_pipe<true, false><<<grid, 512, 0, stream>>>(aq, FIN, Bprot, bprot, bufB, NNODE, FIN);
    }

    const int gG = (NNODE * 64 + 255) / 256;
    // ---- layer 1 ----
    seg_mean_gather<<<gG, 256, 0, stream>>>(bufB, bktRP, cntRP, NNODE, bufE);
    launch_gemm3(bufE, bufA, nullptr, Bp1, bl1 + 256, bufC, 512, true, stream);
    seg_mean_gather<<<gG, 256, 0, stream>>>(bufA, bktPP, cntPP, NNODE, bufE);
    seg_mean_gather<<<gG, 256, 0, stream>>>(bufB, bktPR, cntPR, NNODE, bufF);
    launch_gemm3(bufE, bufF, bufB, Bq1, bq1, bufD, 768, true, stream);

    // ---- layer 2 ----
    seg_mean_gather<<<gG, 256, 0, stream>>>(bufD, bktRP, cntRP, NNODE, bufE);
    launch_gemm3(bufE, bufC, nullptr, Bp2, bl2 + 256, bufA, 512, false, stream);
    seg_mean_gather<<<gG, 256, 0, stream>>>(bufC, bktPP, cntPP, NNODE, bufE);
    seg_mean_gather<<<gG, 256, 0, stream>>>(bufD, bktPR, cntPR, NNODE, bufF);
    launch_gemm3(bufE, bufF, bufD, Bq2, bq2, bufB, 768, false, stream);

    // ---- edge classifiers (2 edges/wave) ----
    edge_dot<<<(EL * 32 + 255) / 256, 256, 0, stream>>>(bufA, bufB, eli_het,  eli_het  + EL, EL, out);
    edge_dot<<<(EL * 32 + 255) / 256, 256, 0, stream>>>(bufB, bufB, eli_homo, eli_homo + EL, EL, out + EL);
}

// Round 5
// 660.207 us; speedup vs baseline: 12.7407x; 1.0593x over previous
//
#include <hip/hip_runtime.h>

using u16 = unsigned short;
using u32 = unsigned int;

#define H 256
#define NNODE 50000
#define CAP 32        // Poisson(6): P(deg>32) ~ 1e-15
#define BM 128
#define BN 128
#define BK 64         // bf16 elems per K tile = 128 bytes/row

typedef __attribute__((ext_vector_type(8))) short bf16x8;
typedef __attribute__((ext_vector_type(4))) float f32x4;
typedef __attribute__((ext_vector_type(4))) unsigned int u32x4;

struct AChunks { const void* p[3]; };

__device__ __forceinline__ u16 f2b(float f) {        // f32 -> bf16 RNE
    u32 u = __builtin_bit_cast(u32, f);
    return (u16)((u + 0x7FFFu + ((u >> 16) & 1u)) >> 16);
}
__device__ __forceinline__ float b2f(u16 h) {
    u32 u = ((u32)h) << 16;
    return __builtin_bit_cast(float, u);
}
__device__ __forceinline__ void gld_lds16(const void* g, void* l) {
    __builtin_amdgcn_global_load_lds(
        (__attribute__((address_space(1))) void*)(void*)g,
        (__attribute__((address_space(3))) void*)l, 16, 0, 0);
}
__device__ __forceinline__ u32 packbf(float a, float b) {
    return (u32)f2b(a) | ((u32)f2b(b) << 16);
}
// truncating pack of 2 f32 -> 2 bf16 in one v_perm_b32
__device__ __forceinline__ u32 pack_trunc(float lo, float hi) {
    return __builtin_amdgcn_perm(__builtin_bit_cast(u32, hi),
                                 __builtin_bit_cast(u32, lo), 0x07060302u);
}

// ---------------------------------------------------------------------------
// Pipelined bf16 MFMA GEMM (bf16 A): C[M,256] = concat_K(A) @ Bw[256,Ktot]^T
// 128x128 tile, BK=64, 512 threads (8 waves, 2m x 4n), dbuf LDS, counted vmcnt.
// ---------------------------------------------------------------------------
template<bool RELU>
__global__ __launch_bounds__(512) void gemm_pipe(
    AChunks ac, int aStride, const u16* __restrict__ Bw,
    const float* __restrict__ bias, u16* __restrict__ C, int M, int Ktot)
{
    __shared__ __align__(16) char As[2][BM * 128];
    __shared__ __align__(16) char Bs[2][BN * 128];

    const int tid = threadIdx.x;
    const int l   = tid & 63;
    const int w   = tid >> 6;          // 0..7
    const int wr  = w >> 2, wc = w & 3;
    const int m0  = blockIdx.x * BM;
    const int n0  = blockIdx.y * BN;
    const int nk  = Ktot >> 6;

    f32x4 acc[4][2];
#pragma unroll
    for (int i = 0; i < 4; ++i)
#pragma unroll
        for (int j = 0; j < 2; ++j) acc[i][j] = f32x4{0.f, 0.f, 0.f, 0.f};

    auto stageB = [&](int k, int bi) {
        int k0 = k * 64;
#pragma unroll
        for (int i = 0; i < 2; ++i) {
            int ci = i * 512 + tid;
            int r = ci >> 3, c16 = ci & 7;
            int sb = (c16 * 16) ^ ((r & 7) << 4);      // pre-swizzled source
            const u16* g = Bw + (size_t)(n0 + r) * Ktot + k0 + (sb >> 1);
            gld_lds16(g, &Bs[bi][ci * 16]);
        }
    };
    auto stageAb = [&](int k, int bi) {
        int k0 = k * 64;
        const u16* base = (const u16*)ac.p[k0 >> 8];
        int kk = k0 & 255;
#pragma unroll
        for (int i = 0; i < 2; ++i) {
            int ci = i * 512 + tid;
            int r = ci >> 3, c16 = ci & 7;
            int row = m0 + r; row = row < M ? row : M - 1;
            int sb = (c16 * 16) ^ ((r & 7) << 4);
            const u16* g = base + (size_t)row * aStride + kk + (sb >> 1);
            gld_lds16(g, &As[bi][ci * 16]);
        }
    };
    auto compute = [&](int bi) {
#pragma unroll
        for (int ks = 0; ks < 2; ++ks) {
            bf16x8 af[4], bfr[2];
#pragma unroll
            for (int mi = 0; mi < 4; ++mi) {
                int r = wr * 64 + mi * 16 + (l & 15);
                int off = (ks * 64 + (l >> 4) * 16) ^ ((r & 7) << 4);
                af[mi] = *(const bf16x8*)&As[bi][r * 128 + off];
            }
#pragma unroll
            for (int ni = 0; ni < 2; ++ni) {
                int r = wc * 32 + ni * 16 + (l & 15);
                int off = (ks * 64 + (l >> 4) * 16) ^ ((r & 7) << 4);
                bfr[ni] = *(const bf16x8*)&Bs[bi][r * 128 + off];
            }
#pragma unroll
            for (int mi = 0; mi < 4; ++mi)
#pragma unroll
                for (int ni = 0; ni < 2; ++ni)
                    acc[mi][ni] = __builtin_amdgcn_mfma_f32_16x16x32_bf16(
                        af[mi], bfr[ni], acc[mi][ni], 0, 0, 0);
        }
    };
    auto body = [&](int k, int cur) {
        asm volatile("s_waitcnt vmcnt(4)" ::: "memory");   // set(k) done
        __builtin_amdgcn_sched_barrier(0);
        __builtin_amdgcn_s_barrier();
        __builtin_amdgcn_sched_barrier(0);
        compute(cur);
        __builtin_amdgcn_sched_barrier(0);
        __builtin_amdgcn_s_barrier();
        __builtin_amdgcn_sched_barrier(0);
        int kq = k + 2; if (kq > nk - 1) kq = nk - 1;  // clamped dup keeps count
        stageB(kq, cur);
        stageAb(kq, cur);
        __builtin_amdgcn_sched_barrier(0);
    };

    stageB(0, 0); stageAb(0, 0);
    __builtin_amdgcn_sched_barrier(0);
    stageB(1, 1); stageAb(1, 1);
    __builtin_amdgcn_sched_barrier(0);
    for (int k = 0; k < nk; k += 2) {   // nk even for all our shapes
        body(k,     0);
        body(k + 1, 1);
    }

    // epilogue: C/D layout col=lane&15, row=(lane>>4)*4+reg
    const int fr = l & 15, fq = l >> 4;
#pragma unroll
    for (int ni = 0; ni < 2; ++ni) {
        int col = n0 + wc * 32 + ni * 16 + fr;
        float bv = bias ? bias[col] : 0.f;
#pragma unroll
        for (int mi = 0; mi < 4; ++mi) {
            int rowb = m0 + wr * 64 + mi * 16 + fq * 4;
#pragma unroll
            for (int j = 0; j < 4; ++j) {
                int row = rowb + j;
                if (row < M) {
                    float v = acc[mi][ni][j] + bv;
                    if (RELU) v = fmaxf(v, 0.f);
                    C[(size_t)row * H + col] = f2b(v);
                }
            }
        }
    }
}

// ---------------------------------------------------------------------------
// Projection GEMM (f32 A staged via global_load_lds, truncating cvt at read):
// C[M,256] = A_f32[M,1280] @ Bw[256,1280]^T + bias.
// BM=128, BN=256 (full width -> grid (391,1), A read ONCE), BK=32.
// LDS: A 2x16KB (f32 128B/row) + B 2x16KB (256 rows x 64B) = 64KB.
// ---------------------------------------------------------------------------
__global__ __launch_bounds__(512) void gemm_proj(
    const float* __restrict__ A, int aStride, const u16* __restrict__ Bw,
    const float* __restrict__ bias, u16* __restrict__ C, int M, int Ktot)
{
    __shared__ __align__(16) char As[2][128 * 128];   // 128 rows x 32 f32
    __shared__ __align__(16) char Bs[2][256 * 64];    // 256 rows x 32 bf16

    const int tid = threadIdx.x;
    const int l   = tid & 63;
    const int w   = tid >> 6;          // 0..7
    const int wr  = w >> 2, wc = w & 3;  // 2m x 4n
    const int m0  = blockIdx.x * 128;
    const int nk  = Ktot >> 5;         // 40

    f32x4 acc[4][4];
#pragma unroll
    for (int i = 0; i < 4; ++i)
#pragma unroll
        for (int j = 0; j < 4; ++j) acc[i][j] = f32x4{0.f, 0.f, 0.f, 0.f};

    auto stageB = [&](int k, int bi) {
        int k0 = k * 32;
#pragma unroll
        for (int i = 0; i < 2; ++i) {
            int ci = i * 512 + tid;          // 0..1023, 16B chunks
            int r = ci >> 2, c4 = ci & 3;    // 256 rows x 4 chunks
            int sb = (c4 * 16) ^ ((r & 3) << 4);
            const u16* g = Bw + (size_t)r * Ktot + k0 + (sb >> 1);
            gld_lds16(g, &Bs[bi][ci * 16]);
        }
    };
    auto stageA = [&](int k, int bi) {
        int k0 = k * 32;
#pragma unroll
        for (int i = 0; i < 2; ++i) {
            int ci = i * 512 + tid;          // 0..1023
            int r = ci >> 3, c8 = ci & 7;    // 128 rows x 8 chunks
            int row = m0 + r; row = row < M ? row : M - 1;
            int sb = (c8 * 16) ^ ((r & 7) << 4);
            const float* g = A + (size_t)row * aStride + k0 + (sb >> 2);
            gld_lds16(g, &As[bi][ci * 16]);
        }
    };
    auto compute = [&](int bi) {
        bf16x8 af[4], bfr[4];
#pragma unroll
        for (int mi = 0; mi < 4; ++mi) {
            int r = wr * 64 + mi * 16 + (l & 15);
            int o0 = ((l >> 4) * 32)      ^ ((r & 7) << 4);
            int o1 = ((l >> 4) * 32 + 16) ^ ((r & 7) << 4);
            f32x4 c0 = *(const f32x4*)&As[bi][r * 128 + o0];
            f32x4 c1 = *(const f32x4*)&As[bi][r * 128 + o1];
            u32x4 ww;
            ww[0] = pack_trunc(c0[0], c0[1]);
            ww[1] = pack_trunc(c0[2], c0[3]);
            ww[2] = pack_trunc(c1[0], c1[1]);
            ww[3] = pack_trunc(c1[2], c1[3]);
            af[mi] = __builtin_bit_cast(bf16x8, ww);
        }
#pragma unroll
        for (int ni = 0; ni < 4; ++ni) {
            int r = wc * 64 + ni * 16 + (l & 15);
            int off = ((l >> 4) * 16) ^ ((r & 3) << 4);
            bfr[ni] = *(const bf16x8*)&Bs[bi][r * 64 + off];
        }
#pragma unroll
        for (int mi = 0; mi < 4; ++mi)
#pragma unroll
            for (int ni = 0; ni < 4; ++ni)
                acc[mi][ni] = __builtin_amdgcn_mfma_f32_16x16x32_bf16(
                    af[mi], bfr[ni], acc[mi][ni], 0, 0, 0);
    };
    auto body = [&](int k, int cur) {
        asm volatile("s_waitcnt vmcnt(4)" ::: "memory");
        __builtin_amdgcn_sched_barrier(0);
        __builtin_amdgcn_s_barrier();
        __builtin_amdgcn_sched_barrier(0);
        compute(cur);
        __builtin_amdgcn_sched_barrier(0);
        __builtin_amdgcn_s_barrier();
        __builtin_amdgcn_sched_barrier(0);
        int kq = k + 2; if (kq > nk - 1) kq = nk - 1;
        stageB(kq, cur);
        stageA(kq, cur);
        __builtin_amdgcn_sched_barrier(0);
    };

    stageB(0, 0); stageA(0, 0);
    __builtin_amdgcn_sched_barrier(0);
    stageB(1, 1); stageA(1, 1);
    __builtin_amdgcn_sched_barrier(0);
    for (int k = 0; k < nk; k += 2) {   // nk = 40, even
        body(k,     0);
        body(k + 1, 1);
    }

    const int fr = l & 15, fq = l >> 4;
#pragma unroll
    for (int ni = 0; ni < 4; ++ni) {
        int col = wc * 64 + ni * 16 + fr;
        float bv = bias ? bias[col] : 0.f;
#pragma unroll
        for (int mi = 0; mi < 4; ++mi) {
            int rowb = m0 + wr * 64 + mi * 16 + fq * 4;
#pragma unroll
            for (int j = 0; j < 4; ++j) {
                int row = rowb + j;
                if (row < M)
                    C[(size_t)row * H + col] = f2b(acc[mi][ni][j] + bv);
            }
        }
    }
}

// ---------------------------------------------------------------------------
// utility kernels
// ---------------------------------------------------------------------------
__global__ __launch_bounds__(256) void fill_zero(float4* __restrict__ p, size_t n4)
{
    size_t i = (size_t)blockIdx.x * blockDim.x + threadIdx.x;
    size_t stride = (size_t)gridDim.x * blockDim.x;
    for (; i < n4; i += stride) p[i] = make_float4(0.f, 0.f, 0.f, 0.f);
}

__global__ __launch_bounds__(256) void build_bucket(
    const int* __restrict__ src, const int* __restrict__ dst, int nE,
    int* __restrict__ cnt, int* __restrict__ bucket)
{
    int i = blockIdx.x * blockDim.x + threadIdx.x;
    if (i >= nE) return;
    int d = dst[i];
    int pos = atomicAdd(&cnt[d], 1);
    if (pos < CAP) bucket[(size_t)d * CAP + pos] = src[i];
}

__global__ __launch_bounds__(256) void seg_mean_gather(
    const u16* __restrict__ feat, const int* __restrict__ bucket,
    const int* __restrict__ cnt, int n_dst, u16* __restrict__ out)
{
    int d = (int)(((size_t)blockIdx.x * blockDim.x + threadIdx.x) >> 6);
    int lane = threadIdx.x & 63;
    if (d >= n_dst) return;
    int c = cnt[d];
    int cc = c < CAP ? c : CAP;
    const int* b = bucket + (size_t)d * CAP;
    float a0 = 0.f, a1 = 0.f, a2 = 0.f, a3 = 0.f;
    int i = 0;
    for (; i + 4 <= cc; i += 4) {            // 4 gathers in flight
        int s0 = b[i], s1 = b[i + 1], s2 = b[i + 2], s3 = b[i + 3];
        uint2 v0 = *(const uint2*)(feat + (size_t)s0 * H + lane * 4);
        uint2 v1 = *(const uint2*)(feat + (size_t)s1 * H + lane * 4);
        uint2 v2 = *(const uint2*)(feat + (size_t)s2 * H + lane * 4);
        uint2 v3 = *(const uint2*)(feat + (size_t)s3 * H + lane * 4);
        a0 += b2f((u16)(v0.x & 0xffff)) + b2f((u16)(v1.x & 0xffff))
            + b2f((u16)(v2.x & 0xffff)) + b2f((u16)(v3.x & 0xffff));
        a1 += b2f((u16)(v0.x >> 16)) + b2f((u16)(v1.x >> 16))
            + b2f((u16)(v2.x >> 16)) + b2f((u16)(v3.x >> 16));
        a2 += b2f((u16)(v0.y & 0xffff)) + b2f((u16)(v1.y & 0xffff))
            + b2f((u16)(v2.y & 0xffff)) + b2f((u16)(v3.y & 0xffff));
        a3 += b2f((u16)(v0.y >> 16)) + b2f((u16)(v1.y >> 16))
            + b2f((u16)(v2.y >> 16)) + b2f((u16)(v3.y >> 16));
    }
    for (; i < cc; ++i) {
        uint2 v = *(const uint2*)(feat + (size_t)b[i] * H + lane * 4);
        a0 += b2f((u16)(v.x & 0xffff));
        a1 += b2f((u16)(v.x >> 16));
        a2 += b2f((u16)(v.y & 0xffff));
        a3 += b2f((u16)(v.y >> 16));
    }
    float inv = 1.0f / fmaxf((float)c, 1.0f);
    uint2 o;
    o.x = packbf(a0 * inv, a1 * inv);
    o.y = packbf(a2 * inv, a3 * inv);
    *(uint2*)(out + (size_t)d * H + lane * 4) = o;
}

// 2 edges per wave: 32 lanes x 16B per edge row
__global__ __launch_bounds__(256) void edge_dot(
    const u16* __restrict__ P, const u16* __restrict__ Q,
    const int* __restrict__ ia, const int* __restrict__ ib,
    int nE, float* __restrict__ out)
{
    int gi = blockIdx.x * 256 + threadIdx.x;
    int e = gi >> 5, l32 = gi & 31;
    if (e >= nE) return;
    uint4 a = *(const uint4*)(P + (size_t)ia[e] * H + l32 * 8);
    uint4 b = *(const uint4*)(Q + (size_t)ib[e] * H + l32 * 8);
    float v = 0.f;
    v += b2f((u16)(a.x & 0xffff)) * b2f((u16)(b.x & 0xffff));
    v += b2f((u16)(a.x >> 16))    * b2f((u16)(b.x >> 16));
    v += b2f((u16)(a.y & 0xffff)) * b2f((u16)(b.y & 0xffff));
    v += b2f((u16)(a.y >> 16))    * b2f((u16)(b.y >> 16));
    v += b2f((u16)(a.z & 0xffff)) * b2f((u16)(b.z & 0xffff));
    v += b2f((u16)(a.z >> 16))    * b2f((u16)(b.z >> 16));
    v += b2f((u16)(a.w & 0xffff)) * b2f((u16)(b.w & 0xffff));
    v += b2f((u16)(a.w >> 16))    * b2f((u16)(b.w >> 16));
#pragma unroll
    for (int off = 16; off; off >>= 1) v += __shfl_xor(v, off);
    if (l32 == 0) out[e] = v;
}

// fused weight pack: 12 items, 1024 elems per block
struct PackTab {
    const float* s1[12]; const float* s2[12]; u16* dst[12];
    int Ks[12], Kdst[12], koff[12], blk0[13];
};
__global__ __launch_bounds__(256) void pack_all(PackTab t)
{
    int b = blockIdx.x;
    int it = 0;
    while (it < 11 && b >= t.blk0[it + 1]) ++it;
    int idx = (b - t.blk0[it]) * 1024 + threadIdx.x * 4;
    int Ks = t.Ks[it];
    if (idx >= 256 * Ks) return;
    int n = idx / Ks;
    int k = idx - n * Ks;
    float4 v = *(const float4*)(t.s1[it] + idx);
    if (t.s2[it]) {
        float4 u = *(const float4*)(t.s2[it] + idx);
        v.x += u.x; v.y += u.y; v.z += u.z; v.w += u.w;
    }
    ushort4 h;
    h.x = f2b(v.x); h.y = f2b(v.y); h.z = f2b(v.z); h.w = f2b(v.w);
    *(ushort4*)(t.dst[it] + (size_t)n * t.Kdst[it] + t.koff[it] + k) = h;
}

__global__ void bias_pair(const float* __restrict__ bl1, const float* __restrict__ bl2,
                          float* __restrict__ bq1, float* __restrict__ bq2)
{
    int i = threadIdx.x;
    if (blockIdx.x == 0) bq1[i] = bl1[i] + bl1[512 + i];
    else                 bq2[i] = bl2[i] + bl2[512 + i];
}

// ---------------------------------------------------------------------------
// host-side helpers
// ---------------------------------------------------------------------------
static inline void launch_gemm3(const void* a0, const void* a1, const void* a2,
                                const u16* Bw, const float* bias, u16* C,
                                int Ktot, bool relu, hipStream_t s)
{
    AChunks ac = {{a0, a1, a2}};
    dim3 grid((NNODE + BM - 1) / BM, H / BN);
    if (relu) gemm_pipe<true><<<grid, 512, 0, s>>>(ac, 256, Bw, bias, C, NNODE, Ktot);
    else      gemm_pipe<false><<<grid, 512, 0, s>>>(ac, 256, Bw, bias, C, NNODE, Ktot);
}

extern "C" void kernel_launch(void* const* d_in, const int* in_sizes, int n_in,
                              void* d_out, int out_size, void* d_ws, size_t ws_size,
                              hipStream_t stream)
{
    const float* x_pep  = (const float*)d_in[0];
    const float* x_prot = (const float*)d_in[1];
    const float* Wpep   = (const float*)d_in[2];
    const float* bpep   = (const float*)d_in[3];
    const float* Wprot  = (const float*)d_in[4];
    const float* bprot  = (const float*)d_in[5];
    const float* Wl1    = (const float*)d_in[6];
    const float* bl1    = (const float*)d_in[7];
    const float* Wr1    = (const float*)d_in[8];
    const float* Wl2    = (const float*)d_in[9];
    const float* bl2    = (const float*)d_in[10];
    const float* Wr2    = (const float*)d_in[11];
    const int* ei_pp    = (const int*)d_in[12];
    const int* ei_rp    = (const int*)d_in[13];
    const int* ei_prot  = (const int*)d_in[14];
    const int* eli_het  = (const int*)d_in[15];
    const int* eli_homo = (const int*)d_in[16];

    const int E  = in_sizes[12] / 2;   // 300000
    const int EL = in_sizes[15] / 2;   // 200000
    const int FIN = in_sizes[2] / H;   // 1280

    float* out = (float*)d_out;

    // ---- workspace carve (~177 MB) ----
    const size_t nodeElems = (size_t)NNODE * H;      // bf16 elems
    u16* bufA = (u16*)d_ws;            // h_pep  -> p2
    u16* bufB = bufA + nodeElems;      // h_prot -> q2
    u16* bufC = bufB + nodeElems;      // p1
    u16* bufD = bufC + nodeElems;      // q1
    u16* bufE = bufD + nodeElems;      // mean scratch 1
    u16* bufF = bufE + nodeElems;      // mean scratch 2
    u16* Bpep  = bufF + nodeElems;
    u16* Bprot = Bpep  + (size_t)256 * 1280;
    u16* Bp1   = Bprot + (size_t)256 * 1280;
    u16* Bq1   = Bp1   + (size_t)256 * 512;
    u16* Bp2   = Bq1   + (size_t)256 * 768;
    u16* Bq2   = Bp2   + (size_t)256 * 512;
    float* bq1 = (float*)(Bq2 + (size_t)256 * 768);
    float* bq2 = bq1 + 256;
    int* cntRP   = (int*)(bq2 + 256);
    int* cntPP   = cntRP + NNODE;
    int* cntPR   = cntPP + NNODE;
    int* bktRP   = cntPR + NNODE;
    int* bktPP   = bktRP + (size_t)NNODE * CAP;
    int* bktPR   = bktPP + (size_t)NNODE * CAP;

    const size_t HH = (size_t)H * H;

    // ---- fused weight pack ----
    PackTab t{};
    int blk = 0, it = 0;
    auto add = [&](const float* s1, const float* s2, u16* d, int Ks, int Kd, int ko) {
        t.s1[it] = s1; t.s2[it] = s2; t.dst[it] = d;
        t.Ks[it] = Ks; t.Kdst[it] = Kd; t.koff[it] = ko;
        t.blk0[it] = blk; blk += (256 * Ks) / 1024; ++it;
    };
    add(Wpep,  nullptr, Bpep,  1280, 1280, 0);
    add(Wprot, nullptr, Bprot, 1280, 1280, 0);
    add(Wl1 + 1 * HH, nullptr,      Bp1, 256, 512, 0);
    add(Wr1 + 1 * HH, nullptr,      Bp1, 256, 512, 256);
    add(Wl1 + 0 * HH, nullptr,      Bq1, 256, 768, 0);
    add(Wl1 + 2 * HH, nullptr,      Bq1, 256, 768, 256);
    add(Wr1 + 0 * HH, Wr1 + 2 * HH, Bq1, 256, 768, 512);
    add(Wl2 + 1 * HH, nullptr,      Bp2, 256, 512, 0);
    add(Wr2 + 1 * HH, nullptr,      Bp2, 256, 512, 256);
    add(Wl2 + 0 * HH, nullptr,      Bq2, 256, 768, 0);
    add(Wl2 + 2 * HH, nullptr,      Bq2, 256, 768, 256);
    add(Wr2 + 0 * HH, Wr2 + 2 * HH, Bq2, 256, 768, 512);
    t.blk0[12] = blk;
    pack_all<<<blk, 256, 0, stream>>>(t);
    bias_pair<<<2, 256, 0, stream>>>(bl1, bl2, bq1, bq2);

    // ---- buckets: built ONCE per edge type, reused by both layers ----
    fill_zero<<<147, 256, 0, stream>>>((float4*)cntRP, (size_t)3 * NNODE / 4);
    build_bucket<<<(E + 255) / 256, 256, 0, stream>>>(ei_rp,   ei_rp + E,   E, cntRP, bktRP);
    build_bucket<<<(E + 255) / 256, 256, 0, stream>>>(ei_pp,   ei_pp + E,   E, cntPP, bktPP);
    build_bucket<<<(E + 255) / 256, 256, 0, stream>>>(ei_prot, ei_prot + E, E, cntPR, bktPR);

    // ---- input projections (f32 A staged to LDS, BN=256, grid (391,1)) ----
    {
        dim3 grid((NNODE + 127) / 128, 1);
        gemm_proj<<<grid, 512, 0, stream>>>(x_pep,  FIN, Bpep,  bpep,  bufA, NNODE, FIN);
        gemm_proj<<<grid, 512, 0, stream>>>(x_prot, FIN, Bprot, bprot, bufB, NNODE, FIN);
    }

    const int gG = (NNODE * 64 + 255) / 256;
    // ---- layer 1 ----
    seg_mean_gather<<<gG, 256, 0, stream>>>(bufB, bktRP, cntRP, NNODE, bufE);
    launch_gemm3(bufE, bufA, nullptr, Bp1, bl1 + 256, bufC, 512, true, stream);
    seg_mean_gather<<<gG, 256, 0, stream>>>(bufA, bktPP, cntPP, NNODE, bufE);
    seg_mean_gather<<<gG, 256, 0, stream>>>(bufB, bktPR, cntPR, NNODE, bufF);
    launch_gemm3(bufE, bufF, bufB, Bq1, bq1, bufD, 768, true, stream);

    // ---- layer 2 ----
    seg_mean_gather<<<gG, 256, 0, stream>>>(bufD, bktRP, cntRP, NNODE, bufE);
    launch_gemm3(bufE, bufC, nullptr, Bp2, bl2 + 256, bufA, 512, false, stream);
    seg_mean_gather<<<gG, 256, 0, stream>>>(bufC, bktPP, cntPP, NNODE, bufE);
    seg_mean_gather<<<gG, 256, 0, stream>>>(bufD, bktPR, cntPR, NNODE, bufF);
    launch_gemm3(bufE, bufF, bufD, Bq2, bq2, bufB, 768, false, stream);

    // ---- edge classifiers (2 edges/wave) ----
    edge_dot<<<(EL * 32 + 255) / 256, 256, 0, stream>>>(bufA, bufB, eli_het,  eli_het  + EL, EL, out);
    edge_dot<<<(EL * 32 + 255) / 256, 256, 0, stream>>>(bufB, bufB, eli_homo, eli_homo + EL, EL, out + EL);
}

// Round 6
// 637.027 us; speedup vs baseline: 13.2043x; 1.0364x over previous
//
#include <hip/hip_runtime.h>

using u16 = unsigned short;
using u32 = unsigned int;

#define H 256
#define NNODE 50000
#define CAP 32        // Poisson(6): P(deg>32) ~ 1e-15
#define BM 128
#define BN 128
#define BK 64         // bf16 elems per K tile = 128 bytes/row

typedef __attribute__((ext_vector_type(8))) short bf16x8;
typedef __attribute__((ext_vector_type(4))) float f32x4;
typedef __attribute__((ext_vector_type(4))) unsigned int u32x4;

struct AChunks { const void* p[3]; };

__device__ __forceinline__ u16 f2b(float f) {        // f32 -> bf16 RNE
    u32 u = __builtin_bit_cast(u32, f);
    return (u16)((u + 0x7FFFu + ((u >> 16) & 1u)) >> 16);
}
__device__ __forceinline__ float b2f(u16 h) {
    u32 u = ((u32)h) << 16;
    return __builtin_bit_cast(float, u);
}
__device__ __forceinline__ void gld_lds16(const void* g, void* l) {
    __builtin_amdgcn_global_load_lds(
        (__attribute__((address_space(1))) void*)(void*)g,
        (__attribute__((address_space(3))) void*)l, 16, 0, 0);
}
__device__ __forceinline__ u32 packbf(float a, float b) {
    return (u32)f2b(a) | ((u32)f2b(b) << 16);
}
// truncating pack of 2 f32 -> 2 bf16 in one v_perm_b32
__device__ __forceinline__ u32 pack_trunc(float lo, float hi) {
    return __builtin_amdgcn_perm(__builtin_bit_cast(u32, hi),
                                 __builtin_bit_cast(u32, lo), 0x07060302u);
}

// ---------------------------------------------------------------------------
// Pipelined bf16 MFMA GEMM (bf16 A): C[M,256] = concat_K(A) @ Bw[256,Ktot]^T
// 128x128 tile, BK=64, 512 threads (8 waves, 2m x 4n), dbuf LDS, counted vmcnt.
// ---------------------------------------------------------------------------
template<bool RELU>
__global__ __launch_bounds__(512) void gemm_pipe(
    AChunks ac, int aStride, const u16* __restrict__ Bw,
    const float* __restrict__ bias, u16* __restrict__ C, int M, int Ktot)
{
    __shared__ __align__(16) char As[2][BM * 128];
    __shared__ __align__(16) char Bs[2][BN * 128];

    const int tid = threadIdx.x;
    const int l   = tid & 63;
    const int w   = tid >> 6;          // 0..7
    const int wr  = w >> 2, wc = w & 3;
    const int m0  = blockIdx.x * BM;
    const int n0  = blockIdx.y * BN;
    const int nk  = Ktot >> 6;

    f32x4 acc[4][2];
#pragma unroll
    for (int i = 0; i < 4; ++i)
#pragma unroll
        for (int j = 0; j < 2; ++j) acc[i][j] = f32x4{0.f, 0.f, 0.f, 0.f};

    auto stageB = [&](int k, int bi) {
        int k0 = k * 64;
#pragma unroll
        for (int i = 0; i < 2; ++i) {
            int ci = i * 512 + tid;
            int r = ci >> 3, c16 = ci & 7;
            int sb = (c16 * 16) ^ ((r & 7) << 4);      // pre-swizzled source
            const u16* g = Bw + (size_t)(n0 + r) * Ktot + k0 + (sb >> 1);
            gld_lds16(g, &Bs[bi][ci * 16]);
        }
    };
    auto stageAb = [&](int k, int bi) {
        int k0 = k * 64;
        const u16* base = (const u16*)ac.p[k0 >> 8];
        int kk = k0 & 255;
#pragma unroll
        for (int i = 0; i < 2; ++i) {
            int ci = i * 512 + tid;
            int r = ci >> 3, c16 = ci & 7;
            int row = m0 + r; row = row < M ? row : M - 1;
            int sb = (c16 * 16) ^ ((r & 7) << 4);
            const u16* g = base + (size_t)row * aStride + kk + (sb >> 1);
            gld_lds16(g, &As[bi][ci * 16]);
        }
    };
    auto compute = [&](int bi) {
#pragma unroll
        for (int ks = 0; ks < 2; ++ks) {
            bf16x8 af[4], bfr[2];
#pragma unroll
            for (int mi = 0; mi < 4; ++mi) {
                int r = wr * 64 + mi * 16 + (l & 15);
                int off = (ks * 64 + (l >> 4) * 16) ^ ((r & 7) << 4);
                af[mi] = *(const bf16x8*)&As[bi][r * 128 + off];
            }
#pragma unroll
            for (int ni = 0; ni < 2; ++ni) {
                int r = wc * 32 + ni * 16 + (l & 15);
                int off = (ks * 64 + (l >> 4) * 16) ^ ((r & 7) << 4);
                bfr[ni] = *(const bf16x8*)&Bs[bi][r * 128 + off];
            }
#pragma unroll
            for (int mi = 0; mi < 4; ++mi)
#pragma unroll
                for (int ni = 0; ni < 2; ++ni)
                    acc[mi][ni] = __builtin_amdgcn_mfma_f32_16x16x32_bf16(
                        af[mi], bfr[ni], acc[mi][ni], 0, 0, 0);
        }
    };
    auto body = [&](int k, int cur) {
        asm volatile("s_waitcnt vmcnt(4)" ::: "memory");   // set(k) done
        __builtin_amdgcn_sched_barrier(0);
        __builtin_amdgcn_s_barrier();
        __builtin_amdgcn_sched_barrier(0);
        compute(cur);
        __builtin_amdgcn_sched_barrier(0);
        __builtin_amdgcn_s_barrier();
        __builtin_amdgcn_sched_barrier(0);
        int kq = k + 2; if (kq > nk - 1) kq = nk - 1;  // clamped dup keeps count
        stageB(kq, cur);
        stageAb(kq, cur);
        __builtin_amdgcn_sched_barrier(0);
    };

    stageB(0, 0); stageAb(0, 0);
    __builtin_amdgcn_sched_barrier(0);
    stageB(1, 1); stageAb(1, 1);
    __builtin_amdgcn_sched_barrier(0);
    for (int k = 0; k < nk; k += 2) {   // nk even for all our shapes
        body(k,     0);
        body(k + 1, 1);
    }

    // epilogue: C/D layout col=lane&15, row=(lane>>4)*4+reg
    const int fr = l & 15, fq = l >> 4;
#pragma unroll
    for (int ni = 0; ni < 2; ++ni) {
        int col = n0 + wc * 32 + ni * 16 + fr;
        float bv = bias ? bias[col] : 0.f;
#pragma unroll
        for (int mi = 0; mi < 4; ++mi) {
            int rowb = m0 + wr * 64 + mi * 16 + fq * 4;
#pragma unroll
            for (int j = 0; j < 4; ++j) {
                int row = rowb + j;
                if (row < M) {
                    float v = acc[mi][ni][j] + bv;
                    if (RELU) v = fmaxf(v, 0.f);
                    C[(size_t)row * H + col] = f2b(v);
                }
            }
        }
    }
}

// ---------------------------------------------------------------------------
// Projection GEMM v2: C[M,256] = A_f32[M,1280] @ Bw[256,1280]^T + bias.
// BM=256, BN=256, BK=32, 1024 threads (16 waves, 4m x 4n).
// Triple-buffered LDS (144 KB, 1 block/CU), depth-3 prefetch, vmcnt(6).
// Grid (196,1): one co-resident generation, A read exactly once.
// ---------------------------------------------------------------------------
__global__ __launch_bounds__(1024) void gemm_proj(
    const float* __restrict__ A, int aStride, const u16* __restrict__ Bw,
    const float* __restrict__ bias, u16* __restrict__ C, int M, int Ktot)
{
    __shared__ __align__(16) char As[3][256 * 128];   // 3 x 32 KB (256 rows x 32 f32)
    __shared__ __align__(16) char Bs[3][256 * 64];    // 3 x 16 KB (256 rows x 32 bf16)

    const int tid = threadIdx.x;
    const int l   = tid & 63;
    const int w   = tid >> 6;            // 0..15
    const int wq  = w >> 2, wc = w & 3;  // 4m x 4n
    const int m0  = blockIdx.x * 256;
    const int nk  = Ktot >> 5;           // 40

    f32x4 acc[4][4];
#pragma unroll
    for (int i = 0; i < 4; ++i)
#pragma unroll
        for (int j = 0; j < 4; ++j) acc[i][j] = f32x4{0.f, 0.f, 0.f, 0.f};

    // stage tile k into buffer bi: 3 gld_lds per thread (1 B + 2 A)
    auto stage = [&](int k, int bi) {
        int k0 = k * 32;
        char* asb = &As[0][0] + bi * (256 * 128);
        char* bsb = &Bs[0][0] + bi * (256 * 64);
        {   // B: 256 rows x 4 chunks = 1024, one per thread
            int ci = tid;
            int r = ci >> 2, c4 = ci & 3;
            int sb = (c4 * 16) ^ (((r >> 2) & 3) << 4);   // conflict-free swizzle
            const u16* g = Bw + (size_t)r * Ktot + k0 + (sb >> 1);
            gld_lds16(g, bsb + ci * 16);
        }
#pragma unroll
        for (int i = 0; i < 2; ++i) {   // A: 256 rows x 8 chunks = 2048, two per thread
            int ci = i * 1024 + tid;
            int r = ci >> 3, c8 = ci & 7;
            int row = m0 + r; row = row < M ? row : M - 1;
            int sb = (c8 * 16) ^ ((r & 7) << 4);
            const float* g = A + (size_t)row * aStride + k0 + (sb >> 2);
            gld_lds16(g, asb + ci * 16);
        }
    };

    auto compute = [&](int bi) {
        const char* asb = &As[0][0] + bi * (256 * 128);
        const char* bsb = &Bs[0][0] + bi * (256 * 64);
        bf16x8 af[4], bfr[4];
#pragma unroll
        for (int mi = 0; mi < 4; ++mi) {
            int r = wq * 64 + mi * 16 + (l & 15);
            int sw = (r & 7) << 4;
            int base = (l >> 4) * 32;
            f32x4 c0 = *(const f32x4*)(asb + r * 128 + (base ^ sw));
            f32x4 c1 = *(const f32x4*)(asb + r * 128 + ((base + 16) ^ sw));
            u32x4 ww;
            ww[0] = pack_trunc(c0[0], c0[1]);
            ww[1] = pack_trunc(c0[2], c0[3]);
            ww[2] = pack_trunc(c1[0], c1[1]);
            ww[3] = pack_trunc(c1[2], c1[3]);
            af[mi] = __builtin_bit_cast(bf16x8, ww);
        }
#pragma unroll
        for (int ni = 0; ni < 4; ++ni) {
            int r = wc * 64 + ni * 16 + (l & 15);
            int off = ((l >> 4) * 16) ^ (((r >> 2) & 3) << 4);
            bfr[ni] = *(const bf16x8*)(bsb + r * 64 + off);
        }
#pragma unroll
        for (int mi = 0; mi < 4; ++mi)
#pragma unroll
            for (int ni = 0; ni < 4; ++ni)
                acc[mi][ni] = __builtin_amdgcn_mfma_f32_16x16x32_bf16(
                    af[mi], bfr[ni], acc[mi][ni], 0, 0, 0);
    };

    // prologue: fill 3 buffers (9 loads/thread in flight)
    stage(0, 0); __builtin_amdgcn_sched_barrier(0);
    stage(1, 1); __builtin_amdgcn_sched_barrier(0);
    stage(2, 2); __builtin_amdgcn_sched_barrier(0);

    int cur = 0;
    for (int k = 0; k < nk; ++k) {
        asm volatile("s_waitcnt vmcnt(6)" ::: "memory");   // stage(k) landed; k+1,k+2 in flight
        __builtin_amdgcn_sched_barrier(0);
        __builtin_amdgcn_s_barrier();
        __builtin_amdgcn_sched_barrier(0);
        compute(cur);
        __builtin_amdgcn_sched_barrier(0);
        __builtin_amdgcn_s_barrier();
        __builtin_amdgcn_sched_barrier(0);
        int kq = k + 3; if (kq > nk - 1) kq = nk - 1;      // clamped dup keeps count
        stage(kq, cur);
        __builtin_amdgcn_sched_barrier(0);
        cur = (cur == 2) ? 0 : cur + 1;
    }
    asm volatile("s_waitcnt vmcnt(0)" ::: "memory");       // drain before exit

    // epilogue: C/D layout col=lane&15, row=(lane>>4)*4+reg
    const int fr = l & 15, fq = l >> 4;
#pragma unroll
    for (int ni = 0; ni < 4; ++ni) {
        int col = wc * 64 + ni * 16 + fr;
        float bv = bias ? bias[col] : 0.f;
#pragma unroll
        for (int mi = 0; mi < 4; ++mi) {
            int rowb = m0 + wq * 64 + mi * 16 + fq * 4;
#pragma unroll
            for (int j = 0; j < 4; ++j) {
                int row = rowb + j;
                if (row < M)
                    C[(size_t)row * H + col] = f2b(acc[mi][ni][j] + bv);
            }
        }
    }
}

// ---------------------------------------------------------------------------
// utility kernels
// ---------------------------------------------------------------------------
__global__ __launch_bounds__(256) void fill_zero(float4* __restrict__ p, size_t n4)
{
    size_t i = (size_t)blockIdx.x * blockDim.x + threadIdx.x;
    size_t stride = (size_t)gridDim.x * blockDim.x;
    for (; i < n4; i += stride) p[i] = make_float4(0.f, 0.f, 0.f, 0.f);
}

__global__ __launch_bounds__(256) void build_bucket(
    const int* __restrict__ src, const int* __restrict__ dst, int nE,
    int* __restrict__ cnt, int* __restrict__ bucket)
{
    int i = blockIdx.x * blockDim.x + threadIdx.x;
    if (i >= nE) return;
    int d = dst[i];
    int pos = atomicAdd(&cnt[d], 1);
    if (pos < CAP) bucket[(size_t)d * CAP + pos] = src[i];
}

__global__ __launch_bounds__(256) void seg_mean_gather(
    const u16* __restrict__ feat, const int* __restrict__ bucket,
    const int* __restrict__ cnt, int n_dst, u16* __restrict__ out)
{
    int d = (int)(((size_t)blockIdx.x * blockDim.x + threadIdx.x) >> 6);
    int lane = threadIdx.x & 63;
    if (d >= n_dst) return;
    int c = cnt[d];
    int cc = c < CAP ? c : CAP;
    const int* b = bucket + (size_t)d * CAP;
    float a0 = 0.f, a1 = 0.f, a2 = 0.f, a3 = 0.f;
    int i = 0;
    for (; i + 4 <= cc; i += 4) {            // 4 gathers in flight
        int s0 = b[i], s1 = b[i + 1], s2 = b[i + 2], s3 = b[i + 3];
        uint2 v0 = *(const uint2*)(feat + (size_t)s0 * H + lane * 4);
        uint2 v1 = *(const uint2*)(feat + (size_t)s1 * H + lane * 4);
        uint2 v2 = *(const uint2*)(feat + (size_t)s2 * H + lane * 4);
        uint2 v3 = *(const uint2*)(feat + (size_t)s3 * H + lane * 4);
        a0 += b2f((u16)(v0.x & 0xffff)) + b2f((u16)(v1.x & 0xffff))
            + b2f((u16)(v2.x & 0xffff)) + b2f((u16)(v3.x & 0xffff));
        a1 += b2f((u16)(v0.x >> 16)) + b2f((u16)(v1.x >> 16))
            + b2f((u16)(v2.x >> 16)) + b2f((u16)(v3.x >> 16));
        a2 += b2f((u16)(v0.y & 0xffff)) + b2f((u16)(v1.y & 0xffff))
            + b2f((u16)(v2.y & 0xffff)) + b2f((u16)(v3.y & 0xffff));
        a3 += b2f((u16)(v0.y >> 16)) + b2f((u16)(v1.y >> 16))
            + b2f((u16)(v2.y >> 16)) + b2f((u16)(v3.y >> 16));
    }
    for (; i < cc; ++i) {
        uint2 v = *(const uint2*)(feat + (size_t)b[i] * H + lane * 4);
        a0 += b2f((u16)(v.x & 0xffff));
        a1 += b2f((u16)(v.x >> 16));
        a2 += b2f((u16)(v.y & 0xffff));
        a3 += b2f((u16)(v.y >> 16));
    }
    float inv = 1.0f / fmaxf((float)c, 1.0f);
    uint2 o;
    o.x = packbf(a0 * inv, a1 * inv);
    o.y = packbf(a2 * inv, a3 * inv);
    *(uint2*)(out + (size_t)d * H + lane * 4) = o;
}

// 2 edges per wave: 32 lanes x 16B per edge row
__global__ __launch_bounds__(256) void edge_dot(
    const u16* __restrict__ P, const u16* __restrict__ Q,
    const int* __restrict__ ia, const int* __restrict__ ib,
    int nE, float* __restrict__ out)
{
    int gi = blockIdx.x * 256 + threadIdx.x;
    int e = gi >> 5, l32 = gi & 31;
    if (e >= nE) return;
    uint4 a = *(const uint4*)(P + (size_t)ia[e] * H + l32 * 8);
    uint4 b = *(const uint4*)(Q + (size_t)ib[e] * H + l32 * 8);
    float v = 0.f;
    v += b2f((u16)(a.x & 0xffff)) * b2f((u16)(b.x & 0xffff));
    v += b2f((u16)(a.x >> 16))    * b2f((u16)(b.x >> 16));
    v += b2f((u16)(a.y & 0xffff)) * b2f((u16)(b.y & 0xffff));
    v += b2f((u16)(a.y >> 16))    * b2f((u16)(b.y >> 16));
    v += b2f((u16)(a.z & 0xffff)) * b2f((u16)(b.z & 0xffff));
    v += b2f((u16)(a.z >> 16))    * b2f((u16)(b.z >> 16));
    v += b2f((u16)(a.w & 0xffff)) * b2f((u16)(b.w & 0xffff));
    v += b2f((u16)(a.w >> 16))    * b2f((u16)(b.w >> 16));
#pragma unroll
    for (int off = 16; off; off >>= 1) v += __shfl_xor(v, off);
    if (l32 == 0) out[e] = v;
}

// fused weight pack: 12 items, 1024 elems per block
struct PackTab {
    const float* s1[12]; const float* s2[12]; u16* dst[12];
    int Ks[12], Kdst[12], koff[12], blk0[13];
};
__global__ __launch_bounds__(256) void pack_all(PackTab t)
{
    int b = blockIdx.x;
    int it = 0;
    while (it < 11 && b >= t.blk0[it + 1]) ++it;
    int idx = (b - t.blk0[it]) * 1024 + threadIdx.x * 4;
    int Ks = t.Ks[it];
    if (idx >= 256 * Ks) return;
    int n = idx / Ks;
    int k = idx - n * Ks;
    float4 v = *(const float4*)(t.s1[it] + idx);
    if (t.s2[it]) {
        float4 u = *(const float4*)(t.s2[it] + idx);
        v.x += u.x; v.y += u.y; v.z += u.z; v.w += u.w;
    }
    ushort4 h;
    h.x = f2b(v.x); h.y = f2b(v.y); h.z = f2b(v.z); h.w = f2b(v.w);
    *(ushort4*)(t.dst[it] + (size_t)n * t.Kdst[it] + t.koff[it] + k) = h;
}

__global__ void bias_pair(const float* __restrict__ bl1, const float* __restrict__ bl2,
                          float* __restrict__ bq1, float* __restrict__ bq2)
{
    int i = threadIdx.x;
    if (blockIdx.x == 0) bq1[i] = bl1[i] + bl1[512 + i];
    else                 bq2[i] = bl2[i] + bl2[512 + i];
}

// ---------------------------------------------------------------------------
// host-side helpers
// ---------------------------------------------------------------------------
static inline void launch_gemm3(const void* a0, const void* a1, const void* a2,
                                const u16* Bw, const float* bias, u16* C,
                                int Ktot, bool relu, hipStream_t s)
{
    AChunks ac = {{a0, a1, a2}};
    dim3 grid((NNODE + BM - 1) / BM, H / BN);
    if (relu) gemm_pipe<true><<<grid, 512, 0, s>>>(ac, 256, Bw, bias, C, NNODE, Ktot);
    else      gemm_pipe<false><<<grid, 512, 0, s>>>(ac, 256, Bw, bias, C, NNODE, Ktot);
}

extern "C" void kernel_launch(void* const* d_in, const int* in_sizes, int n_in,
                              void* d_out, int out_size, void* d_ws, size_t ws_size,
                              hipStream_t stream)
{
    const float* x_pep  = (const float*)d_in[0];
    const float* x_prot = (const float*)d_in[1];
    const float* Wpep   = (const float*)d_in[2];
    const float* bpep   = (const float*)d_in[3];
    const float* Wprot  = (const float*)d_in[4];
    const float* bprot  = (const float*)d_in[5];
    const float* Wl1    = (const float*)d_in[6];
    const float* bl1    = (const float*)d_in[7];
    const float* Wr1    = (const float*)d_in[8];
    const float* Wl2    = (const float*)d_in[9];
    const float* bl2    = (const float*)d_in[10];
    const float* Wr2    = (const float*)d_in[11];
    const int* ei_pp    = (const int*)d_in[12];
    const int* ei_rp    = (const int*)d_in[13];
    const int* ei_prot  = (const int*)d_in[14];
    const int* eli_het  = (const int*)d_in[15];
    const int* eli_homo = (const int*)d_in[16];

    const int E  = in_sizes[12] / 2;   // 300000
    const int EL = in_sizes[15] / 2;   // 200000
    const int FIN = in_sizes[2] / H;   // 1280

    float* out = (float*)d_out;

    // ---- workspace carve (~177 MB) ----
    const size_t nodeElems = (size_t)NNODE * H;      // bf16 elems
    u16* bufA = (u16*)d_ws;            // h_pep  -> p2
    u16* bufB = bufA + nodeElems;      // h_prot -> q2
    u16* bufC = bufB + nodeElems;      // p1
    u16* bufD = bufC + nodeElems;      // q1
    u16* bufE = bufD + nodeElems;      // mean scratch 1
    u16* bufF = bufE + nodeElems;      // mean scratch 2
    u16* Bpep  = bufF + nodeElems;
    u16* Bprot = Bpep  + (size_t)256 * 1280;
    u16* Bp1   = Bprot + (size_t)256 * 1280;
    u16* Bq1   = Bp1   + (size_t)256 * 512;
    u16* Bp2   = Bq1   + (size_t)256 * 768;
    u16* Bq2   = Bp2   + (size_t)256 * 512;
    float* bq1 = (float*)(Bq2 + (size_t)256 * 768);
    float* bq2 = bq1 + 256;
    int* cntRP   = (int*)(bq2 + 256);
    int* cntPP   = cntRP + NNODE;
    int* cntPR   = cntPP + NNODE;
    int* bktRP   = cntPR + NNODE;
    int* bktPP   = bktRP + (size_t)NNODE * CAP;
    int* bktPR   = bktPP + (size_t)NNODE * CAP;

    const size_t HH = (size_t)H * H;

    // ---- fused weight pack ----
    PackTab t{};
    int blk = 0, it = 0;
    auto add = [&](const float* s1, const float* s2, u16* d, int Ks, int Kd, int ko) {
        t.s1[it] = s1; t.s2[it] = s2; t.dst[it] = d;
        t.Ks[it] = Ks; t.Kdst[it] = Kd; t.koff[it] = ko;
        t.blk0[it] = blk; blk += (256 * Ks) / 1024; ++it;
    };
    add(Wpep,  nullptr, Bpep,  1280, 1280, 0);
    add(Wprot, nullptr, Bprot, 1280, 1280, 0);
    add(Wl1 + 1 * HH, nullptr,      Bp1, 256, 512, 0);
    add(Wr1 + 1 * HH, nullptr,      Bp1, 256, 512, 256);
    add(Wl1 + 0 * HH, nullptr,      Bq1, 256, 768, 0);
    add(Wl1 + 2 * HH, nullptr,      Bq1, 256, 768, 256);
    add(Wr1 + 0 * HH, Wr1 + 2 * HH, Bq1, 256, 768, 512);
    add(Wl2 + 1 * HH, nullptr,      Bp2, 256, 512, 0);
    add(Wr2 + 1 * HH, nullptr,      Bp2, 256, 512, 256);
    add(Wl2 + 0 * HH, nullptr,      Bq2, 256, 768, 0);
    add(Wl2 + 2 * HH, nullptr,      Bq2, 256, 768, 256);
    add(Wr2 + 0 * HH, Wr2 + 2 * HH, Bq2, 256, 768, 512);
    t.blk0[12] = blk;
    pack_all<<<blk, 256, 0, stream>>>(t);
    bias_pair<<<2, 256, 0, stream>>>(bl1, bl2, bq1, bq2);

    // ---- buckets: built ONCE per edge type, reused by both layers ----
    fill_zero<<<147, 256, 0, stream>>>((float4*)cntRP, (size_t)3 * NNODE / 4);
    build_bucket<<<(E + 255) / 256, 256, 0, stream>>>(ei_rp,   ei_rp + E,   E, cntRP, bktRP);
    build_bucket<<<(E + 255) / 256, 256, 0, stream>>>(ei_pp,   ei_pp + E,   E, cntPP, bktPP);
    build_bucket<<<(E + 255) / 256, 256, 0, stream>>>(ei_prot, ei_prot + E, E, cntPR, bktPR);

    // ---- input projections (f32 A, depth-3 pipeline, grid (196,1)) ----
    {
        dim3 grid((NNODE + 255) / 256, 1);
        gemm_proj<<<grid, 1024, 0, stream>>>(x_pep,  FIN, Bpep,  bpep,  bufA, NNODE, FIN);
        gemm_proj<<<grid, 1024, 0, stream>>>(x_prot, FIN, Bprot, bprot, bufB, NNODE, FIN);
    }

    const int gG = (NNODE * 64 + 255) / 256;
    // ---- layer 1 ----
    seg_mean_gather<<<gG, 256, 0, stream>>>(bufB, bktRP, cntRP, NNODE, bufE);
    launch_gemm3(bufE, bufA, nullptr, Bp1, bl1 + 256, bufC, 512, true, stream);
    seg_mean_gather<<<gG, 256, 0, stream>>>(bufA, bktPP, cntPP, NNODE, bufE);
    seg_mean_gather<<<gG, 256, 0, stream>>>(bufB, bktPR, cntPR, NNODE, bufF);
    launch_gemm3(bufE, bufF, bufB, Bq1, bq1, bufD, 768, true, stream);

    // ---- layer 2 ----
    seg_mean_gather<<<gG, 256, 0, stream>>>(bufD, bktRP, cntRP, NNODE, bufE);
    launch_gemm3(bufE, bufC, nullptr, Bp2, bl2 + 256, bufA, 512, false, stream);
    seg_mean_gather<<<gG, 256, 0, stream>>>(bufC, bktPP, cntPP, NNODE, bufE);
    seg_mean_gather<<<gG, 256, 0, stream>>>(bufD, bktPR, cntPR, NNODE, bufF);
    launch_gemm3(bufE, bufF, bufD, Bq2, bq2, bufB, 768, false, stream);

    // ---- edge classifiers (2 edges/wave) ----
    edge_dot<<<(EL * 32 + 255) / 256, 256, 0, stream>>>(bufA, bufB, eli_het,  eli_het  + EL, EL, out);
    edge_dot<<<(EL * 32 + 255) / 256, 256, 0, stream>>>(bufB, bufB, eli_homo, eli_homo + EL, EL, out + EL);
}